// Round 1
// baseline (1501.899 us; speedup 1.0000x reference)
//
#include <hip/hip_runtime.h>
#include <hip/hip_bf16.h>

#define EPSF 1e-8f
#define NN 50000
#define DD 128
#define BB 64
#define LL 512
#define PP0 200000
#define PP1 50000
#define SCALE 0.08838834764831845f  // 1/sqrt(128)

__device__ __forceinline__ float logsigf(float x) {
    float s = 1.f / (1.f + __expf(-x));
    return __logf(s + EPSF);
}

__device__ __forceinline__ float red32(float v) {
    #pragma unroll
    for (int m = 16; m >= 1; m >>= 1) v += __shfl_xor(v, m, 64);
    return v;
}

__device__ __forceinline__ float dot4(float4 a, float4 b) {
    return a.x * b.x + a.y * b.y + a.z * b.z + a.w * b.w;
}

// ---------------- Edge task 0: 2*P0 pairs, 32 lanes per pair ----------------
__global__ __launch_bounds__(256) void edge0_kernel(
    const float* __restrict__ emb, const int* __restrict__ pos,
    const int* __restrict__ neg, float* __restrict__ acc)
{
    int gid = blockIdx.x * 256 + threadIdx.x;
    int grp = gid >> 5;            // 0 .. 2*P0-1
    int sub = threadIdx.x & 31;
    __shared__ float bs;
    if (threadIdx.x == 0) bs = 0.f;
    __syncthreads();

    bool isneg = grp >= PP0;
    const int* e = isneg ? (neg + 2 * (grp - PP0)) : (pos + 2 * grp);
    int h = e[0], t = e[1];
    float4 a = ((const float4*)(emb + (size_t)h * DD))[sub];
    float4 b = ((const float4*)(emb + (size_t)t * DD))[sub];
    float d = red32(dot4(a, b));
    if (sub == 0) {
        float c = logsigf(isneg ? -d : d);
        atomicAdd(&bs, c);
    }
    __syncthreads();
    if (threadIdx.x == 0) atomicAdd(acc, bs);
}

// ---------------- ps1[i] = dot(emb[pos_e1[i,0]], emb[pos_e1[i,1]]) ----------
__global__ __launch_bounds__(256) void ps1_kernel(
    const float* __restrict__ emb, const int* __restrict__ pos1,
    float* __restrict__ ps1)
{
    int gid = blockIdx.x * 256 + threadIdx.x;
    int grp = gid >> 5;            // 0 .. P1-1
    int sub = threadIdx.x & 31;
    int h = pos1[2 * grp], t = pos1[2 * grp + 1];
    float4 a = ((const float4*)(emb + (size_t)h * DD))[sub];
    float4 b = ((const float4*)(emb + (size_t)t * DD))[sub];
    float d = red32(dot4(a, b));
    if (sub == 0) ps1[grp] = d;
}

// ---------------- Edge task 1: P1*4 triples ---------------------------------
__global__ __launch_bounds__(256) void edge1_kernel(
    const float* __restrict__ emb, const int* __restrict__ pos1,
    const int* __restrict__ neg1, const float* __restrict__ ps1,
    float* __restrict__ acc)
{
    int gid = blockIdx.x * 256 + threadIdx.x;
    int grp = gid >> 5;            // 0 .. 4*P1-1
    int sub = threadIdx.x & 31;
    __shared__ float bs;
    if (threadIdx.x == 0) bs = 0.f;
    __syncthreads();

    int i = grp % PP1;
    int ph = pos1[2 * i], pt = pos1[2 * i + 1];
    int nh = neg1[2 * grp], nt = neg1[2 * grp + 1];
    float4 vph = ((const float4*)(emb + (size_t)ph * DD))[sub];
    float4 vpt = ((const float4*)(emb + (size_t)pt * DD))[sub];
    float4 vnh = ((const float4*)(emb + (size_t)nh * DD))[sub];
    float4 vnt = ((const float4*)(emb + (size_t)nt * DD))[sub];
    float sh = dot4(vnh, vpt);
    float st = dot4(vph, vnt);
    sh = red32(sh);
    st = red32(st);
    if (sub == 0) {
        float ps = ps1[i];
        float c = logsigf(ps - sh) + logsigf(ps - st);
        atomicAdd(&bs, c);
    }
    __syncthreads();
    if (threadIdx.x == 0) atomicAdd(acc + 1, bs);
}

// ---------------- QKV projection: out^T[b][t][r] = (W @ I)[r][t] ------------
// grid (16 t-tiles, 3 matrices, 64 users), block 256
__global__ __launch_bounds__(256) void proj_kernel(
    const float* __restrict__ emb, const float* __restrict__ Wrep,
    const float* __restrict__ Wq, const float* __restrict__ Wk,
    const float* __restrict__ Wv, const int* __restrict__ qseq,
    const int* __restrict__ cseq, float* __restrict__ QT,
    float* __restrict__ KT, float* __restrict__ VT)
{
    int b = blockIdx.z;
    int which = blockIdx.y;
    int t0 = blockIdx.x * 32;
    const float* W = (which == 0) ? Wq : ((which == 1) ? Wk : Wv);
    float* OUT = (which == 0) ? QT : ((which == 1) ? KT : VT);

    __shared__ float Wl[128 * 36];
    __shared__ float Il[32 * 36];
    __shared__ int qs[32];
    __shared__ int cs[32];
    int tid = threadIdx.x;
    if (tid < 32) {
        qs[tid] = qseq[b * LL + t0 + tid];
        cs[tid] = cseq[b * LL + t0 + tid];
    }
    __syncthreads();

    int tx = tid & 31;   // r = 4*tx + ri
    int ty = tid >> 5;   // t = 4*ty + tj
    float accv[4][4] = {{0.f}};  // [tj][ri]

    for (int d0 = 0; d0 < 128; d0 += 32) {
        for (int idx = tid; idx < 128 * 32; idx += 256) {
            int r = idx >> 5, dc = idx & 31;
            Wl[r * 36 + dc] = W[r * 128 + d0 + dc];
        }
        for (int idx = tid; idx < 32 * 32; idx += 256) {
            int t = idx >> 5, dc = idx & 31;
            int d = d0 + dc;
            Il[t * 36 + dc] = emb[(size_t)qs[t] * DD + d] + Wrep[d * 2 + cs[t]];
        }
        __syncthreads();
        for (int dc = 0; dc < 32; ++dc) {
            float wv[4], iv[4];
            #pragma unroll
            for (int i = 0; i < 4; i++) wv[i] = Wl[(4 * tx + i) * 36 + dc];
            #pragma unroll
            for (int j = 0; j < 4; j++) iv[j] = Il[(4 * ty + j) * 36 + dc];
            #pragma unroll
            for (int j = 0; j < 4; j++)
                #pragma unroll
                for (int i = 0; i < 4; i++)
                    accv[j][i] += iv[j] * wv[i];
        }
        __syncthreads();
    }
    #pragma unroll
    for (int j = 0; j < 4; j++) {
        int t = t0 + 4 * ty + j;
        float4 v = make_float4(accv[j][0], accv[j][1], accv[j][2], accv[j][3]);
        *(float4*)(OUT + ((size_t)b * LL + t) * DD + 4 * tx) = v;
    }
}

// ---------------- Flash attention fp32: grid (16 qtiles, 64 users) ----------
__global__ __launch_bounds__(256) void attn_kernel(
    const float* __restrict__ QT, const float* __restrict__ KT,
    const float* __restrict__ VT, float* __restrict__ BvT)
{
    int qt = blockIdx.x;
    int b = blockIdx.y;
    __shared__ float Qt[32 * 129];
    __shared__ float Kt[32 * 129];
    __shared__ float Vt[32 * 129];
    __shared__ float Sl[32 * 33];
    __shared__ float mj[32], lj[32], alphaj[32];
    int tid = threadIdx.x;

    for (int idx = tid; idx < 32 * 128; idx += 256) {
        int j = idx >> 7, d = idx & 127;
        Qt[j * 129 + d] = QT[((size_t)b * LL + qt * 32 + j) * DD + d];
    }
    if (tid < 32) { mj[tid] = -INFINITY; lj[tid] = 0.f; }

    int dg = tid & 31, jg = tid >> 5;   // PV phase: d = dg + 32*dd, j = 4*jg + jj
    int ig = tid & 15, jg2 = tid >> 4;  // S phase: i = 2*ig + ii, j = 2*jg2 + jj
    float Bacc[4][4] = {{0.f}};         // [jj][dd]
    __syncthreads();

    for (int kt = 0; kt <= qt; ++kt) {
        for (int idx = tid; idx < 32 * 128; idx += 256) {
            int i = idx >> 7, d = idx & 127;
            Kt[i * 129 + d] = KT[((size_t)b * LL + kt * 32 + i) * DD + d];
            Vt[i * 129 + d] = VT[((size_t)b * LL + kt * 32 + i) * DD + d];
        }
        __syncthreads();

        // scores: 2x2 per thread
        float s00 = 0.f, s01 = 0.f, s10 = 0.f, s11 = 0.f;
        int i0 = 2 * ig, j0 = 2 * jg2;
        for (int d = 0; d < 128; ++d) {
            float k0 = Kt[i0 * 129 + d], k1 = Kt[(i0 + 1) * 129 + d];
            float q0 = Qt[j0 * 129 + d], q1 = Qt[(j0 + 1) * 129 + d];
            s00 += k0 * q0; s01 += k0 * q1;
            s10 += k1 * q0; s11 += k1 * q1;
        }
        {
            int gi0 = kt * 32 + i0, gj0 = qt * 32 + j0;
            Sl[i0 * 33 + j0]           = (gi0     <= gj0    ) ? s00 * SCALE : -INFINITY;
            Sl[i0 * 33 + j0 + 1]       = (gi0     <= gj0 + 1) ? s01 * SCALE : -INFINITY;
            Sl[(i0 + 1) * 33 + j0]     = (gi0 + 1 <= gj0    ) ? s10 * SCALE : -INFINITY;
            Sl[(i0 + 1) * 33 + j0 + 1] = (gi0 + 1 <= gj0 + 1) ? s11 * SCALE : -INFINITY;
        }
        __syncthreads();

        // online softmax owners (one thread per query column)
        if (tid < 32) {
            int j = tid;
            float tm = -INFINITY;
            for (int i = 0; i < 32; i++) tm = fmaxf(tm, Sl[i * 33 + j]);
            float mnew = fmaxf(mj[j], tm);
            alphaj[j] = __expf(mj[j] - mnew);  // exp(-inf - finite) = 0 on first tile
            mj[j] = mnew;
        }
        __syncthreads();

        // P = exp(S - m)
        for (int idx = tid; idx < 1024; idx += 256) {
            int i = idx >> 5, j = idx & 31;
            Sl[i * 33 + j] = __expf(Sl[i * 33 + j] - mj[j]);
        }
        __syncthreads();

        // l update
        if (tid < 32) {
            int j = tid;
            float rs = 0.f;
            for (int i = 0; i < 32; i++) rs += Sl[i * 33 + j];
            lj[j] = lj[j] * alphaj[j] + rs;
        }

        // PV accumulate
        float al[4];
        #pragma unroll
        for (int jj = 0; jj < 4; jj++) al[jj] = alphaj[4 * jg + jj];
        #pragma unroll
        for (int jj = 0; jj < 4; jj++)
            #pragma unroll
            for (int dd = 0; dd < 4; dd++)
                Bacc[jj][dd] *= al[jj];
        for (int i = 0; i < 32; ++i) {
            float p[4], v[4];
            #pragma unroll
            for (int jj = 0; jj < 4; jj++) p[jj] = Sl[i * 33 + 4 * jg + jj];
            #pragma unroll
            for (int dd = 0; dd < 4; dd++) v[dd] = Vt[i * 129 + dg + 32 * dd];
            #pragma unroll
            for (int jj = 0; jj < 4; jj++)
                #pragma unroll
                for (int dd = 0; dd < 4; dd++)
                    Bacc[jj][dd] += p[jj] * v[dd];
        }
        __syncthreads();
    }

    #pragma unroll
    for (int jj = 0; jj < 4; jj++) {
        int j = 4 * jg + jj;
        float inv = 1.f / lj[j];
        #pragma unroll
        for (int dd = 0; dd < 4; dd++) {
            BvT[((size_t)b * LL + qt * 32 + j) * DD + dg + 32 * dd] = Bacc[jj][dd] * inv;
        }
    }
}

// ---------------- O = Head_agg @ Bv : grid (16 t-tiles, 64 users) -----------
__global__ __launch_bounds__(256) void head_kernel(
    const float* __restrict__ H, const float* __restrict__ BvT,
    float* __restrict__ OT)
{
    int b = blockIdx.y;
    int t0 = blockIdx.x * 32;
    __shared__ float Wl[128 * 36];
    __shared__ float Il[32 * 36];
    int tid = threadIdx.x;
    int tx = tid & 31;
    int ty = tid >> 5;
    float accv[4][4] = {{0.f}};

    for (int d0 = 0; d0 < 128; d0 += 32) {
        for (int idx = tid; idx < 128 * 32; idx += 256) {
            int r = idx >> 5, dc = idx & 31;
            Wl[r * 36 + dc] = H[r * 128 + d0 + dc];
        }
        for (int idx = tid; idx < 32 * 32; idx += 256) {
            int t = idx >> 5, dc = idx & 31;
            Il[t * 36 + dc] = BvT[((size_t)b * LL + t0 + t) * DD + d0 + dc];
        }
        __syncthreads();
        for (int dc = 0; dc < 32; ++dc) {
            float wv[4], iv[4];
            #pragma unroll
            for (int i = 0; i < 4; i++) wv[i] = Wl[(4 * tx + i) * 36 + dc];
            #pragma unroll
            for (int j = 0; j < 4; j++) iv[j] = Il[(4 * ty + j) * 36 + dc];
            #pragma unroll
            for (int j = 0; j < 4; j++)
                #pragma unroll
                for (int i = 0; i < 4; i++)
                    accv[j][i] += iv[j] * wv[i];
        }
        __syncthreads();
    }
    #pragma unroll
    for (int j = 0; j < 4; j++) {
        int t = t0 + 4 * ty + j;
        float4 v = make_float4(accv[j][0], accv[j][1], accv[j][2], accv[j][3]);
        *(float4*)(OT + ((size_t)b * LL + t) * DD + 4 * tx) = v;
    }
}

// ---------------- prediction loss: B*L groups, 32 lanes each ----------------
__global__ __launch_bounds__(256) void pred_kernel(
    const float* __restrict__ OT, const float* __restrict__ emb,
    const float* __restrict__ uinit, const int* __restrict__ qseq,
    const int* __restrict__ cseq, float* __restrict__ acc)
{
    int gid = blockIdx.x * 256 + threadIdx.x;
    int grp = gid >> 5;            // 0 .. B*L-1
    int sub = threadIdx.x & 31;
    __shared__ float bs;
    if (threadIdx.x == 0) bs = 0.f;
    __syncthreads();

    int b = grp >> 9;
    int t = grp & 511;
    const float* u = (t == 0) ? uinit : (OT + ((size_t)b * LL + (t - 1)) * DD);
    int qi = qseq[b * LL + t];
    float4 uv = ((const float4*)u)[sub];
    float4 ev = ((const float4*)(emb + (size_t)qi * DD))[sub];
    float s = red32(dot4(uv, ev));
    if (sub == 0) {
        float c = (float)cseq[b * LL + t];
        float pred = 1.f / (1.f + __expf(-s));
        float term = c * __logf(pred + EPSF) + (1.f - c) * __logf(1.f - pred + EPSF);
        atomicAdd(&bs, term);
    }
    __syncthreads();
    if (threadIdx.x == 0) atomicAdd(acc + 2, bs);
}

// ---------------- final combine ---------------------------------------------
__global__ void combine_kernel(
    const float* __restrict__ acc, const float* __restrict__ sd0p,
    const float* __restrict__ sd1p, const float* __restrict__ sdqp,
    float* __restrict__ out)
{
    if (threadIdx.x == 0 && blockIdx.x == 0) {
        float l0 = -acc[0], l1 = -acc[1], ls = -acc[2];
        float s0 = *sd0p, s1 = *sd1p, ss = *sdqp;
        float tf = l0 / (s0 * s0 + EPSF) + 400000.f * logf(s0 + EPSF)
                 + l1 / (s1 * s1 + EPSF) + 400000.f * logf(s1 + EPSF)
                 + ls / (ss * ss + EPSF) + 512.f * logf(ss + EPSF);
        out[0] = tf;
    }
}

extern "C" void kernel_launch(void* const* d_in, const int* in_sizes, int n_in,
                              void* d_out, int out_size, void* d_ws, size_t ws_size,
                              hipStream_t stream) {
    const float* emb   = (const float*)d_in[0];
    const float* Wrep  = (const float*)d_in[1];
    const float* Wq    = (const float*)d_in[2];
    const float* Wk    = (const float*)d_in[3];
    const float* Wv    = (const float*)d_in[4];
    const float* Hd    = (const float*)d_in[5];
    const float* uinit = (const float*)d_in[6];
    const float* sd0   = (const float*)d_in[7];
    const float* sd1   = (const float*)d_in[8];
    const float* sdq   = (const float*)d_in[9];
    const int* pe0 = (const int*)d_in[10];
    const int* ne0 = (const int*)d_in[11];
    const int* pe1 = (const int*)d_in[12];
    const int* ne1 = (const int*)d_in[13];
    const int* qs  = (const int*)d_in[14];
    const int* cs  = (const int*)d_in[15];

    float* ws = (float*)d_ws;
    float* acc = ws;                 // 16 floats (3 used)
    float* ps1 = ws + 16;            // P1 floats
    const size_t SZ = (size_t)BB * LL * DD;   // 4,194,304 floats
    float* QT  = ws + 50016;
    float* KT  = QT + SZ;
    float* VT  = KT + SZ;
    float* BvT = VT + SZ;
    float* OT  = BvT + SZ;           // total ~84.1 MB

    hipMemsetAsync(acc, 0, 16 * sizeof(float), stream);

    edge0_kernel<<<2 * PP0 / 8, 256, 0, stream>>>(emb, pe0, ne0, acc);
    ps1_kernel<<<PP1 / 8, 256, 0, stream>>>(emb, pe1, ps1);
    edge1_kernel<<<4 * PP1 / 8, 256, 0, stream>>>(emb, pe1, ne1, ps1, acc);

    proj_kernel<<<dim3(16, 3, 64), 256, 0, stream>>>(emb, Wrep, Wq, Wk, Wv,
                                                     qs, cs, QT, KT, VT);
    attn_kernel<<<dim3(16, 64), 256, 0, stream>>>(QT, KT, VT, BvT);
    head_kernel<<<dim3(16, 64), 256, 0, stream>>>(Hd, BvT, OT);
    pred_kernel<<<BB * LL / 8, 256, 0, stream>>>(OT, emb, uinit, qs, cs, acc);

    combine_kernel<<<1, 64, 0, stream>>>(acc, sd0, sd1, sdq, (float*)d_out);
}

// Round 2
// 587.343 us; speedup vs baseline: 2.5571x; 2.5571x over previous
//
#include <hip/hip_runtime.h>
#include <hip/hip_bf16.h>

#define EPSF 1e-8f
#define NN 50000
#define DD 128
#define BB 64
#define LL 512
#define PP0 200000
#define PP1 50000
#define SCALE 0.08838834764831845f  // 1/sqrt(128)

__device__ __forceinline__ float logsigf(float x) {
    float s = 1.f / (1.f + __expf(-x));
    return __logf(s + EPSF);
}

// reduce across the 32-lane half-wave (lanes i and i^m stay in-half for m<32)
__device__ __forceinline__ float red32(float v) {
    #pragma unroll
    for (int m = 16; m >= 1; m >>= 1) v += __shfl_xor(v, m, 64);
    return v;
}

// full 64-lane reduce
__device__ __forceinline__ float red64(float v) {
    #pragma unroll
    for (int m = 32; m >= 1; m >>= 1) v += __shfl_xor(v, m, 64);
    return v;
}

__device__ __forceinline__ float dot4(float4 a, float4 b) {
    return a.x * b.x + a.y * b.y + a.z * b.z + a.w * b.w;
}

// block-level: every thread holds `local`; sum and single-atomic to dst
__device__ __forceinline__ void block_atomic_sum(float local, float* dst) {
    local = red64(local);
    __shared__ float w4[4];
    if ((threadIdx.x & 63) == 0) w4[threadIdx.x >> 6] = local;
    __syncthreads();
    if (threadIdx.x == 0) atomicAdd(dst, w4[0] + w4[1] + w4[2] + w4[3]);
}

// ---------------- Edge task 0: grid-stride, 32 lanes per pair ---------------
__global__ __launch_bounds__(256) void edge0_kernel(
    const float* __restrict__ emb, const int* __restrict__ pos,
    const int* __restrict__ neg, float* __restrict__ acc)
{
    int sub = threadIdx.x & 31;
    int half = (blockIdx.x * 256 + threadIdx.x) >> 5;
    int nhalf = gridDim.x * 8;
    float local = 0.f;
    for (int grp = half; grp < 2 * PP0; grp += nhalf) {
        bool isneg = grp >= PP0;
        const int* e = isneg ? (neg + 2 * (grp - PP0)) : (pos + 2 * grp);
        int h = e[0], t = e[1];
        float4 a = ((const float4*)(emb + (size_t)h * DD))[sub];
        float4 b = ((const float4*)(emb + (size_t)t * DD))[sub];
        float d = red32(dot4(a, b));
        if (sub == 0) local += logsigf(isneg ? -d : d);
    }
    block_atomic_sum(local, acc);
}

// ---------------- Edge task 1: grid-stride over i, pos pair reused x4 -------
__global__ __launch_bounds__(256) void edge1_kernel(
    const float* __restrict__ emb, const int* __restrict__ pos1,
    const int* __restrict__ neg1, float* __restrict__ acc)
{
    int sub = threadIdx.x & 31;
    int half = (blockIdx.x * 256 + threadIdx.x) >> 5;
    int nhalf = gridDim.x * 8;
    float local = 0.f;
    for (int i = half; i < PP1; i += nhalf) {
        int ph = pos1[2 * i], pt = pos1[2 * i + 1];
        float4 vph = ((const float4*)(emb + (size_t)ph * DD))[sub];
        float4 vpt = ((const float4*)(emb + (size_t)pt * DD))[sub];
        float ps = red32(dot4(vph, vpt));
        #pragma unroll
        for (int m = 0; m < 4; m++) {
            int g = m * PP1 + i;
            int nh = neg1[2 * g], nt = neg1[2 * g + 1];
            float4 vnh = ((const float4*)(emb + (size_t)nh * DD))[sub];
            float4 vnt = ((const float4*)(emb + (size_t)nt * DD))[sub];
            float sh = red32(dot4(vnh, vpt));
            float st = red32(dot4(vph, vnt));
            if (sub == 0) local += logsigf(ps - sh) + logsigf(ps - st);
        }
    }
    block_atomic_sum(local, acc + 1);
}

// ---------------- QKV projection: out^T[b][t][r] = (W @ I)[r][t] ------------
// grid (16 t-tiles, 3 matrices, 64 users), block 256
__global__ __launch_bounds__(256) void proj_kernel(
    const float* __restrict__ emb, const float* __restrict__ Wrep,
    const float* __restrict__ Wq, const float* __restrict__ Wk,
    const float* __restrict__ Wv, const int* __restrict__ qseq,
    const int* __restrict__ cseq, float* __restrict__ QT,
    float* __restrict__ KT, float* __restrict__ VT)
{
    int b = blockIdx.z;
    int which = blockIdx.y;
    int t0 = blockIdx.x * 32;
    const float* W = (which == 0) ? Wq : ((which == 1) ? Wk : Wv);
    float* OUT = (which == 0) ? QT : ((which == 1) ? KT : VT);

    __shared__ float Wl[128 * 36];
    __shared__ float Il[32 * 36];
    __shared__ int qs[32];
    __shared__ int cs[32];
    int tid = threadIdx.x;
    if (tid < 32) {
        qs[tid] = qseq[b * LL + t0 + tid];
        cs[tid] = cseq[b * LL + t0 + tid];
    }
    __syncthreads();

    int tx = tid & 31;   // r = 4*tx + ri
    int ty = tid >> 5;   // t = 4*ty + tj
    float accv[4][4] = {{0.f}};  // [tj][ri]

    for (int d0 = 0; d0 < 128; d0 += 32) {
        for (int idx = tid; idx < 128 * 32; idx += 256) {
            int r = idx >> 5, dc = idx & 31;
            Wl[r * 36 + dc] = W[r * 128 + d0 + dc];
        }
        for (int idx = tid; idx < 32 * 32; idx += 256) {
            int t = idx >> 5, dc = idx & 31;
            int d = d0 + dc;
            Il[t * 36 + dc] = emb[(size_t)qs[t] * DD + d] + Wrep[d * 2 + cs[t]];
        }
        __syncthreads();
        for (int dc = 0; dc < 32; ++dc) {
            float wv[4], iv[4];
            #pragma unroll
            for (int i = 0; i < 4; i++) wv[i] = Wl[(4 * tx + i) * 36 + dc];
            #pragma unroll
            for (int j = 0; j < 4; j++) iv[j] = Il[(4 * ty + j) * 36 + dc];
            #pragma unroll
            for (int j = 0; j < 4; j++)
                #pragma unroll
                for (int i = 0; i < 4; i++)
                    accv[j][i] += iv[j] * wv[i];
        }
        __syncthreads();
    }
    #pragma unroll
    for (int j = 0; j < 4; j++) {
        int t = t0 + 4 * ty + j;
        float4 v = make_float4(accv[j][0], accv[j][1], accv[j][2], accv[j][3]);
        *(float4*)(OUT + ((size_t)b * LL + t) * DD + 4 * tx) = v;
    }
}

// ---------------- Flash attention fp32: grid (16 qtiles, 64 users) ----------
__global__ __launch_bounds__(256) void attn_kernel(
    const float* __restrict__ QT, const float* __restrict__ KT,
    const float* __restrict__ VT, float* __restrict__ BvT)
{
    int qt = blockIdx.x;
    int b = blockIdx.y;
    __shared__ float Qt[32 * 129];
    __shared__ float Kt[32 * 129];
    __shared__ float Vt[32 * 129];
    __shared__ float Sl[32 * 33];
    __shared__ float mj[32], lj[32], alphaj[32];
    int tid = threadIdx.x;

    for (int idx = tid; idx < 32 * 128; idx += 256) {
        int j = idx >> 7, d = idx & 127;
        Qt[j * 129 + d] = QT[((size_t)b * LL + qt * 32 + j) * DD + d];
    }
    if (tid < 32) { mj[tid] = -INFINITY; lj[tid] = 0.f; }

    int dg = tid & 31, jg = tid >> 5;   // PV phase: d = dg + 32*dd, j = 4*jg + jj
    int ig = tid & 15, jg2 = tid >> 4;  // S phase: i = 2*ig + ii, j = 2*jg2 + jj
    float Bacc[4][4] = {{0.f}};         // [jj][dd]
    __syncthreads();

    for (int kt = 0; kt <= qt; ++kt) {
        for (int idx = tid; idx < 32 * 128; idx += 256) {
            int i = idx >> 7, d = idx & 127;
            Kt[i * 129 + d] = KT[((size_t)b * LL + kt * 32 + i) * DD + d];
            Vt[i * 129 + d] = VT[((size_t)b * LL + kt * 32 + i) * DD + d];
        }
        __syncthreads();

        // scores: 2x2 per thread
        float s00 = 0.f, s01 = 0.f, s10 = 0.f, s11 = 0.f;
        int i0 = 2 * ig, j0 = 2 * jg2;
        for (int d = 0; d < 128; ++d) {
            float k0 = Kt[i0 * 129 + d], k1 = Kt[(i0 + 1) * 129 + d];
            float q0 = Qt[j0 * 129 + d], q1 = Qt[(j0 + 1) * 129 + d];
            s00 += k0 * q0; s01 += k0 * q1;
            s10 += k1 * q0; s11 += k1 * q1;
        }
        {
            int gi0 = kt * 32 + i0, gj0 = qt * 32 + j0;
            Sl[i0 * 33 + j0]           = (gi0     <= gj0    ) ? s00 * SCALE : -INFINITY;
            Sl[i0 * 33 + j0 + 1]       = (gi0     <= gj0 + 1) ? s01 * SCALE : -INFINITY;
            Sl[(i0 + 1) * 33 + j0]     = (gi0 + 1 <= gj0    ) ? s10 * SCALE : -INFINITY;
            Sl[(i0 + 1) * 33 + j0 + 1] = (gi0 + 1 <= gj0 + 1) ? s11 * SCALE : -INFINITY;
        }
        __syncthreads();

        // online softmax owners (one thread per query column)
        if (tid < 32) {
            int j = tid;
            float tm = -INFINITY;
            for (int i = 0; i < 32; i++) tm = fmaxf(tm, Sl[i * 33 + j]);
            float mnew = fmaxf(mj[j], tm);
            alphaj[j] = __expf(mj[j] - mnew);  // exp(-inf - finite) = 0 on first tile
            mj[j] = mnew;
        }
        __syncthreads();

        // P = exp(S - m)
        for (int idx = tid; idx < 1024; idx += 256) {
            int i = idx >> 5, j = idx & 31;
            Sl[i * 33 + j] = __expf(Sl[i * 33 + j] - mj[j]);
        }
        __syncthreads();

        // l update
        if (tid < 32) {
            int j = tid;
            float rs = 0.f;
            for (int i = 0; i < 32; i++) rs += Sl[i * 33 + j];
            lj[j] = lj[j] * alphaj[j] + rs;
        }

        // PV accumulate
        float al[4];
        #pragma unroll
        for (int jj = 0; jj < 4; jj++) al[jj] = alphaj[4 * jg + jj];
        #pragma unroll
        for (int jj = 0; jj < 4; jj++)
            #pragma unroll
            for (int dd = 0; dd < 4; dd++)
                Bacc[jj][dd] *= al[jj];
        for (int i = 0; i < 32; ++i) {
            float p[4], v[4];
            #pragma unroll
            for (int jj = 0; jj < 4; jj++) p[jj] = Sl[i * 33 + 4 * jg + jj];
            #pragma unroll
            for (int dd = 0; dd < 4; dd++) v[dd] = Vt[i * 129 + dg + 32 * dd];
            #pragma unroll
            for (int jj = 0; jj < 4; jj++)
                #pragma unroll
                for (int dd = 0; dd < 4; dd++)
                    Bacc[jj][dd] += p[jj] * v[dd];
        }
        __syncthreads();
    }

    #pragma unroll
    for (int jj = 0; jj < 4; jj++) {
        int j = 4 * jg + jj;
        float inv = 1.f / lj[j];
        #pragma unroll
        for (int dd = 0; dd < 4; dd++) {
            BvT[((size_t)b * LL + qt * 32 + j) * DD + dg + 32 * dd] = Bacc[jj][dd] * inv;
        }
    }
}

// ---------------- O = Head_agg @ Bv : grid (16 t-tiles, 64 users) -----------
__global__ __launch_bounds__(256) void head_kernel(
    const float* __restrict__ H, const float* __restrict__ BvT,
    float* __restrict__ OT)
{
    int b = blockIdx.y;
    int t0 = blockIdx.x * 32;
    __shared__ float Wl[128 * 36];
    __shared__ float Il[32 * 36];
    int tid = threadIdx.x;
    int tx = tid & 31;
    int ty = tid >> 5;
    float accv[4][4] = {{0.f}};

    for (int d0 = 0; d0 < 128; d0 += 32) {
        for (int idx = tid; idx < 128 * 32; idx += 256) {
            int r = idx >> 5, dc = idx & 31;
            Wl[r * 36 + dc] = H[r * 128 + d0 + dc];
        }
        for (int idx = tid; idx < 32 * 32; idx += 256) {
            int t = idx >> 5, dc = idx & 31;
            Il[t * 36 + dc] = BvT[((size_t)b * LL + t0 + t) * DD + d0 + dc];
        }
        __syncthreads();
        for (int dc = 0; dc < 32; ++dc) {
            float wv[4], iv[4];
            #pragma unroll
            for (int i = 0; i < 4; i++) wv[i] = Wl[(4 * tx + i) * 36 + dc];
            #pragma unroll
            for (int j = 0; j < 4; j++) iv[j] = Il[(4 * ty + j) * 36 + dc];
            #pragma unroll
            for (int j = 0; j < 4; j++)
                #pragma unroll
                for (int i = 0; i < 4; i++)
                    accv[j][i] += iv[j] * wv[i];
        }
        __syncthreads();
    }
    #pragma unroll
    for (int j = 0; j < 4; j++) {
        int t = t0 + 4 * ty + j;
        float4 v = make_float4(accv[j][0], accv[j][1], accv[j][2], accv[j][3]);
        *(float4*)(OT + ((size_t)b * LL + t) * DD + 4 * tx) = v;
    }
}

// ---------------- prediction loss: grid-stride, 32 lanes per (b,t) ----------
__global__ __launch_bounds__(256) void pred_kernel(
    const float* __restrict__ OT, const float* __restrict__ emb,
    const float* __restrict__ uinit, const int* __restrict__ qseq,
    const int* __restrict__ cseq, float* __restrict__ acc)
{
    int sub = threadIdx.x & 31;
    int half = (blockIdx.x * 256 + threadIdx.x) >> 5;
    int nhalf = gridDim.x * 8;
    float local = 0.f;
    for (int grp = half; grp < BB * LL; grp += nhalf) {
        int b = grp >> 9;
        int t = grp & 511;
        const float* u = (t == 0) ? uinit : (OT + ((size_t)b * LL + (t - 1)) * DD);
        int qi = qseq[b * LL + t];
        float4 uv = ((const float4*)u)[sub];
        float4 ev = ((const float4*)(emb + (size_t)qi * DD))[sub];
        float s = red32(dot4(uv, ev));
        if (sub == 0) {
            float c = (float)cseq[b * LL + t];
            float pred = 1.f / (1.f + __expf(-s));
            local += c * __logf(pred + EPSF) + (1.f - c) * __logf(1.f - pred + EPSF);
        }
    }
    block_atomic_sum(local, acc + 2);
}

// ---------------- final combine ---------------------------------------------
__global__ void combine_kernel(
    const float* __restrict__ acc, const float* __restrict__ sd0p,
    const float* __restrict__ sd1p, const float* __restrict__ sdqp,
    float* __restrict__ out)
{
    if (threadIdx.x == 0 && blockIdx.x == 0) {
        float l0 = -acc[0], l1 = -acc[1], ls = -acc[2];
        float s0 = *sd0p, s1 = *sd1p, ss = *sdqp;
        float tf = l0 / (s0 * s0 + EPSF) + 400000.f * logf(s0 + EPSF)
                 + l1 / (s1 * s1 + EPSF) + 400000.f * logf(s1 + EPSF)
                 + ls / (ss * ss + EPSF) + 512.f * logf(ss + EPSF);
        out[0] = tf;
    }
}

extern "C" void kernel_launch(void* const* d_in, const int* in_sizes, int n_in,
                              void* d_out, int out_size, void* d_ws, size_t ws_size,
                              hipStream_t stream) {
    const float* emb   = (const float*)d_in[0];
    const float* Wrep  = (const float*)d_in[1];
    const float* Wq    = (const float*)d_in[2];
    const float* Wk    = (const float*)d_in[3];
    const float* Wv    = (const float*)d_in[4];
    const float* Hd    = (const float*)d_in[5];
    const float* uinit = (const float*)d_in[6];
    const float* sd0   = (const float*)d_in[7];
    const float* sd1   = (const float*)d_in[8];
    const float* sdq   = (const float*)d_in[9];
    const int* pe0 = (const int*)d_in[10];
    const int* ne0 = (const int*)d_in[11];
    const int* pe1 = (const int*)d_in[12];
    const int* ne1 = (const int*)d_in[13];
    const int* qs  = (const int*)d_in[14];
    const int* cs  = (const int*)d_in[15];

    float* ws = (float*)d_ws;
    float* acc = ws;                 // 16 floats (3 used)
    const size_t SZ = (size_t)BB * LL * DD;   // 4,194,304 floats
    float* QT  = ws + 16;
    float* KT  = QT + SZ;
    float* VT  = KT + SZ;
    float* BvT = VT + SZ;
    float* OT  = BvT + SZ;           // total ~84 MB

    hipMemsetAsync(acc, 0, 16 * sizeof(float), stream);

    edge0_kernel<<<1024, 256, 0, stream>>>(emb, pe0, ne0, acc);
    edge1_kernel<<<1024, 256, 0, stream>>>(emb, pe1, ne1, acc);

    proj_kernel<<<dim3(16, 3, 64), 256, 0, stream>>>(emb, Wrep, Wq, Wk, Wv,
                                                     qs, cs, QT, KT, VT);
    attn_kernel<<<dim3(16, 64), 256, 0, stream>>>(QT, KT, VT, BvT);
    head_kernel<<<dim3(16, 64), 256, 0, stream>>>(Hd, BvT, OT);
    pred_kernel<<<512, 256, 0, stream>>>(OT, emb, uinit, qs, cs, acc);

    combine_kernel<<<1, 64, 0, stream>>>(acc, sd0, sd1, sdq, (float*)d_out);
}

// Round 3
// 369.422 us; speedup vs baseline: 4.0655x; 1.5899x over previous
//
#include <hip/hip_runtime.h>
#include <hip/hip_bf16.h>

#define EPSF 1e-8f
#define NN 50000
#define DD 128
#define BB 64
#define LL 512
#define PP0 200000
#define PP1 50000
#define SCALE 0.08838834764831845f  // 1/sqrt(128)

typedef float f4v __attribute__((ext_vector_type(4)));
typedef short s8v __attribute__((ext_vector_type(8)));
typedef short s4v __attribute__((ext_vector_type(4)));

__device__ __forceinline__ float logsigf(float x) {
    float s = 1.f / (1.f + __expf(-x));
    return __logf(s + EPSF);
}

__device__ __forceinline__ float red32(float v) {
    #pragma unroll
    for (int m = 16; m >= 1; m >>= 1) v += __shfl_xor(v, m, 64);
    return v;
}

__device__ __forceinline__ float red64(float v) {
    #pragma unroll
    for (int m = 32; m >= 1; m >>= 1) v += __shfl_xor(v, m, 64);
    return v;
}

__device__ __forceinline__ float dot4(float4 a, float4 b) {
    return a.x * b.x + a.y * b.y + a.z * b.z + a.w * b.w;
}

__device__ __forceinline__ void block_atomic_sum(float local, float* dst) {
    local = red64(local);
    __shared__ float w4[4];
    if ((threadIdx.x & 63) == 0) w4[threadIdx.x >> 6] = local;
    __syncthreads();
    if (threadIdx.x == 0) atomicAdd(dst, w4[0] + w4[1] + w4[2] + w4[3]);
}

// round-to-nearest-even float -> bf16 bits
__device__ __forceinline__ unsigned short f2bf(float f) {
    unsigned u = __float_as_uint(f);
    unsigned r = (u + 0x7fffu + ((u >> 16) & 1u)) >> 16;
    return (unsigned short)r;
}

// ---------------- Edge task 0: grid-stride, 32 lanes per pair ---------------
__global__ __launch_bounds__(256) void edge0_kernel(
    const float* __restrict__ emb, const int* __restrict__ pos,
    const int* __restrict__ neg, float* __restrict__ acc)
{
    int sub = threadIdx.x & 31;
    int half = (blockIdx.x * 256 + threadIdx.x) >> 5;
    int nhalf = gridDim.x * 8;
    float local = 0.f;
    for (int grp = half; grp < 2 * PP0; grp += nhalf) {
        bool isneg = grp >= PP0;
        const int* e = isneg ? (neg + 2 * (grp - PP0)) : (pos + 2 * grp);
        int h = e[0], t = e[1];
        float4 a = ((const float4*)(emb + (size_t)h * DD))[sub];
        float4 b = ((const float4*)(emb + (size_t)t * DD))[sub];
        float d = red32(dot4(a, b));
        if (sub == 0) local += logsigf(isneg ? -d : d);
    }
    block_atomic_sum(local, acc);
}

// ---------------- Edge task 1: grid-stride over i, pos pair reused x4 -------
__global__ __launch_bounds__(256) void edge1_kernel(
    const float* __restrict__ emb, const int* __restrict__ pos1,
    const int* __restrict__ neg1, float* __restrict__ acc)
{
    int sub = threadIdx.x & 31;
    int half = (blockIdx.x * 256 + threadIdx.x) >> 5;
    int nhalf = gridDim.x * 8;
    float local = 0.f;
    for (int i = half; i < PP1; i += nhalf) {
        int ph = pos1[2 * i], pt = pos1[2 * i + 1];
        float4 vph = ((const float4*)(emb + (size_t)ph * DD))[sub];
        float4 vpt = ((const float4*)(emb + (size_t)pt * DD))[sub];
        float ps = red32(dot4(vph, vpt));
        #pragma unroll
        for (int m = 0; m < 4; m++) {
            int g = m * PP1 + i;
            int nh = neg1[2 * g], nt = neg1[2 * g + 1];
            float4 vnh = ((const float4*)(emb + (size_t)nh * DD))[sub];
            float4 vnt = ((const float4*)(emb + (size_t)nt * DD))[sub];
            float sh = red32(dot4(vnh, vpt));
            float st = red32(dot4(vph, vnt));
            if (sub == 0) local += logsigf(ps - sh) + logsigf(ps - st);
        }
    }
    block_atomic_sum(local, acc + 1);
}

// ---------------- QKV projection: out^T[b][t][r] = (W @ I)[r][t] ------------
__global__ __launch_bounds__(256) void proj_kernel(
    const float* __restrict__ emb, const float* __restrict__ Wrep,
    const float* __restrict__ Wq, const float* __restrict__ Wk,
    const float* __restrict__ Wv, const int* __restrict__ qseq,
    const int* __restrict__ cseq, float* __restrict__ QT,
    float* __restrict__ KT, float* __restrict__ VT)
{
    int b = blockIdx.z;
    int which = blockIdx.y;
    int t0 = blockIdx.x * 32;
    const float* W = (which == 0) ? Wq : ((which == 1) ? Wk : Wv);
    float* OUT = (which == 0) ? QT : ((which == 1) ? KT : VT);

    __shared__ float Wl[128 * 36];
    __shared__ float Il[32 * 36];
    __shared__ int qs[32];
    __shared__ int cs[32];
    int tid = threadIdx.x;
    if (tid < 32) {
        qs[tid] = qseq[b * LL + t0 + tid];
        cs[tid] = cseq[b * LL + t0 + tid];
    }
    __syncthreads();

    int tx = tid & 31;
    int ty = tid >> 5;
    float accv[4][4] = {{0.f}};

    for (int d0 = 0; d0 < 128; d0 += 32) {
        for (int idx = tid; idx < 128 * 32; idx += 256) {
            int r = idx >> 5, dc = idx & 31;
            Wl[r * 36 + dc] = W[r * 128 + d0 + dc];
        }
        for (int idx = tid; idx < 32 * 32; idx += 256) {
            int t = idx >> 5, dc = idx & 31;
            int d = d0 + dc;
            Il[t * 36 + dc] = emb[(size_t)qs[t] * DD + d] + Wrep[d * 2 + cs[t]];
        }
        __syncthreads();
        for (int dc = 0; dc < 32; ++dc) {
            float wv[4], iv[4];
            #pragma unroll
            for (int i = 0; i < 4; i++) wv[i] = Wl[(4 * tx + i) * 36 + dc];
            #pragma unroll
            for (int j = 0; j < 4; j++) iv[j] = Il[(4 * ty + j) * 36 + dc];
            #pragma unroll
            for (int j = 0; j < 4; j++)
                #pragma unroll
                for (int i = 0; i < 4; i++)
                    accv[j][i] += iv[j] * wv[i];
        }
        __syncthreads();
    }
    #pragma unroll
    for (int j = 0; j < 4; j++) {
        int t = t0 + 4 * ty + j;
        float4 v = make_float4(accv[j][0], accv[j][1], accv[j][2], accv[j][3]);
        *(float4*)(OUT + ((size_t)b * LL + t) * DD + 4 * tx) = v;
    }
}

// ---------------- Flash attention, bf16 MFMA --------------------------------
// 512 blocks; block i / i+256 carry complementary qt so each CU's resident
// pair sums to 9 k-tiles (load balance). 4 waves/block; wave w owns queries
// [qt*64 + 16w, +16). LDS 45 KB -> 3 blocks/CU.
__global__ __launch_bounds__(256) void attn_mfma_kernel(
    const float* __restrict__ QT, const float* __restrict__ KT,
    const float* __restrict__ VT, float* __restrict__ BvT)
{
    int id = blockIdx.x;
    int r0 = id & 255;
    int b = r0 & 63;
    int qt = (id >> 8) ? (7 - (r0 >> 6)) : (r0 >> 6);

    __shared__ unsigned short K_lds[64 * 136];   // [key][d], pad +8 bf16
    __shared__ unsigned short Vt_lds[128 * 72];  // [d][key], pad +8 bf16
    __shared__ unsigned short P_lds[64 * 72];    // [query][key], pad +8 bf16

    int tid = threadIdx.x;
    int w = tid >> 6;
    int lane = tid & 63;
    int n = lane & 15;
    int quad = lane >> 4;
    int gj = qt * 64 + w * 16 + n;   // this lane's query column

    // Q fragments (B-operand): lane holds Q[n][32c + quad*8 .. +8), bf16
    s8v qfrag[4];
    {
        const float* qrow = QT + ((size_t)(b * LL) + (size_t)gj) * DD;
        #pragma unroll
        for (int c = 0; c < 4; c++) {
            float4 q0 = *(const float4*)&qrow[c * 32 + quad * 8];
            float4 q1 = *(const float4*)&qrow[c * 32 + quad * 8 + 4];
            s8v f;
            f[0] = (short)f2bf(q0.x); f[1] = (short)f2bf(q0.y);
            f[2] = (short)f2bf(q0.z); f[3] = (short)f2bf(q0.w);
            f[4] = (short)f2bf(q1.x); f[5] = (short)f2bf(q1.y);
            f[6] = (short)f2bf(q1.z); f[7] = (short)f2bf(q1.w);
            qfrag[c] = f;
        }
    }

    f4v oacc[8];   // O[query=quad*4+reg][d=dt*16+n], 16 queries x 128 d per wave
    #pragma unroll
    for (int dt = 0; dt < 8; dt++) oacc[dt] = (f4v){0.f, 0.f, 0.f, 0.f};
    float m_run = -INFINITY, l_run = 0.f;

    for (int kt = 0; kt <= qt; ++kt) {
        __syncthreads();   // prior iteration done with K/V LDS
        // stage K [i][d] and V^T [d][i] as bf16
        #pragma unroll
        for (int rep = 0; rep < 8; rep++) {
            int idx = rep * 1024 + tid * 4;
            int i = idx >> 7, d = idx & 127;
            size_t g = ((size_t)(b * LL) + kt * 64 + i) * DD + d;
            float4 kv = *(const float4*)&KT[g];
            float4 vv = *(const float4*)&VT[g];
            s4v kp;
            kp[0] = (short)f2bf(kv.x); kp[1] = (short)f2bf(kv.y);
            kp[2] = (short)f2bf(kv.z); kp[3] = (short)f2bf(kv.w);
            *(s4v*)&K_lds[i * 136 + d] = kp;
            Vt_lds[(d + 0) * 72 + i] = f2bf(vv.x);
            Vt_lds[(d + 1) * 72 + i] = f2bf(vv.y);
            Vt_lds[(d + 2) * 72 + i] = f2bf(vv.z);
            Vt_lds[(d + 3) * 72 + i] = f2bf(vv.w);
        }
        __syncthreads();

        // S[key][query] = K . Q^T for this wave's 16-query strip, 64 keys
        f4v sacc[4];
        #pragma unroll
        for (int mt = 0; mt < 4; mt++) sacc[mt] = (f4v){0.f, 0.f, 0.f, 0.f};
        #pragma unroll
        for (int c = 0; c < 4; c++) {
            #pragma unroll
            for (int mt = 0; mt < 4; mt++) {
                s8v af = *(const s8v*)&K_lds[(mt * 16 + n) * 136 + c * 32 + quad * 8];
                sacc[mt] = __builtin_amdgcn_mfma_f32_16x16x32_bf16(af, qfrag[c], sacc[mt], 0, 0, 0);
            }
        }

        // scale + causal mask + column max (across the 4 quads holding col n)
        bool diag = (kt == qt);
        float mloc = -INFINITY;
        #pragma unroll
        for (int mt = 0; mt < 4; mt++) {
            #pragma unroll
            for (int rr = 0; rr < 4; rr++) {
                float s = sacc[mt][rr] * SCALE;
                if (diag && (kt * 64 + mt * 16 + quad * 4 + rr) > gj) s = -INFINITY;
                sacc[mt][rr] = s;
                mloc = fmaxf(mloc, s);
            }
        }
        mloc = fmaxf(mloc, __shfl_xor(mloc, 16));
        mloc = fmaxf(mloc, __shfl_xor(mloc, 32));
        float mnew = fmaxf(m_run, mloc);
        float alpha = __expf(m_run - mnew);   // 0 on first tile
        m_run = mnew;

        // P = exp(S - m), write own query rows to LDS (bf16), row-sum
        float rsum = 0.f;
        #pragma unroll
        for (int mt = 0; mt < 4; mt++) {
            s4v pp;
            #pragma unroll
            for (int rr = 0; rr < 4; rr++) {
                float p = __expf(sacc[mt][rr] - mnew);
                rsum += p;
                pp[rr] = (short)f2bf(p);
            }
            *(s4v*)&P_lds[(w * 16 + n) * 72 + mt * 16 + quad * 4] = pp;
        }
        rsum += __shfl_xor(rsum, 16);
        rsum += __shfl_xor(rsum, 32);
        l_run = l_run * alpha + rsum;

        // rescale O accumulator: alpha for query quad*4+rr via lane broadcast
        #pragma unroll
        for (int rr = 0; rr < 4; rr++) {
            float a_r = __shfl(alpha, quad * 4 + rr);
            #pragma unroll
            for (int dt = 0; dt < 8; dt++) oacc[dt][rr] *= a_r;
        }

        // O += P x V  (A = P^T rows [wave's queries], B = V^T columns)
        #pragma unroll
        for (int cc = 0; cc < 2; cc++) {
            s8v pf = *(const s8v*)&P_lds[(w * 16 + n) * 72 + cc * 32 + quad * 8];
            #pragma unroll
            for (int dt = 0; dt < 8; dt++) {
                s8v vf = *(const s8v*)&Vt_lds[(dt * 16 + n) * 72 + cc * 32 + quad * 8];
                oacc[dt] = __builtin_amdgcn_mfma_f32_16x16x32_bf16(pf, vf, oacc[dt], 0, 0, 0);
            }
        }
    }

    // epilogue: divide by l, store fp32
    float linv = 1.f / l_run;
    #pragma unroll
    for (int rr = 0; rr < 4; rr++) {
        float li = __shfl(linv, quad * 4 + rr);
        int t = qt * 64 + w * 16 + quad * 4 + rr;
        float* orow = BvT + ((size_t)(b * LL) + t) * DD;
        #pragma unroll
        for (int dt = 0; dt < 8; dt++)
            orow[dt * 16 + n] = oacc[dt][rr] * li;
    }
}

// ---------------- O = Head_agg @ Bv : grid (16 t-tiles, 64 users) -----------
__global__ __launch_bounds__(256) void head_kernel(
    const float* __restrict__ H, const float* __restrict__ BvT,
    float* __restrict__ OT)
{
    int b = blockIdx.y;
    int t0 = blockIdx.x * 32;
    __shared__ float Wl[128 * 36];
    __shared__ float Il[32 * 36];
    int tid = threadIdx.x;
    int tx = tid & 31;
    int ty = tid >> 5;
    float accv[4][4] = {{0.f}};

    for (int d0 = 0; d0 < 128; d0 += 32) {
        for (int idx = tid; idx < 128 * 32; idx += 256) {
            int r = idx >> 5, dc = idx & 31;
            Wl[r * 36 + dc] = H[r * 128 + d0 + dc];
        }
        for (int idx = tid; idx < 32 * 32; idx += 256) {
            int t = idx >> 5, dc = idx & 31;
            Il[t * 36 + dc] = BvT[((size_t)b * LL + t0 + t) * DD + d0 + dc];
        }
        __syncthreads();
        for (int dc = 0; dc < 32; ++dc) {
            float wv[4], iv[4];
            #pragma unroll
            for (int i = 0; i < 4; i++) wv[i] = Wl[(4 * tx + i) * 36 + dc];
            #pragma unroll
            for (int j = 0; j < 4; j++) iv[j] = Il[(4 * ty + j) * 36 + dc];
            #pragma unroll
            for (int j = 0; j < 4; j++)
                #pragma unroll
                for (int i = 0; i < 4; i++)
                    accv[j][i] += iv[j] * wv[i];
        }
        __syncthreads();
    }
    #pragma unroll
    for (int j = 0; j < 4; j++) {
        int t = t0 + 4 * ty + j;
        float4 v = make_float4(accv[j][0], accv[j][1], accv[j][2], accv[j][3]);
        *(float4*)(OT + ((size_t)b * LL + t) * DD + 4 * tx) = v;
    }
}

// ---------------- prediction loss: grid-stride, 32 lanes per (b,t) ----------
__global__ __launch_bounds__(256) void pred_kernel(
    const float* __restrict__ OT, const float* __restrict__ emb,
    const float* __restrict__ uinit, const int* __restrict__ qseq,
    const int* __restrict__ cseq, float* __restrict__ acc)
{
    int sub = threadIdx.x & 31;
    int half = (blockIdx.x * 256 + threadIdx.x) >> 5;
    int nhalf = gridDim.x * 8;
    float local = 0.f;
    for (int grp = half; grp < BB * LL; grp += nhalf) {
        int b = grp >> 9;
        int t = grp & 511;
        const float* u = (t == 0) ? uinit : (OT + ((size_t)b * LL + (t - 1)) * DD);
        int qi = qseq[b * LL + t];
        float4 uv = ((const float4*)u)[sub];
        float4 ev = ((const float4*)(emb + (size_t)qi * DD))[sub];
        float s = red32(dot4(uv, ev));
        if (sub == 0) {
            float c = (float)cseq[b * LL + t];
            float pred = 1.f / (1.f + __expf(-s));
            local += c * __logf(pred + EPSF) + (1.f - c) * __logf(1.f - pred + EPSF);
        }
    }
    block_atomic_sum(local, acc + 2);
}

// ---------------- final combine ---------------------------------------------
__global__ void combine_kernel(
    const float* __restrict__ acc, const float* __restrict__ sd0p,
    const float* __restrict__ sd1p, const float* __restrict__ sdqp,
    float* __restrict__ out)
{
    if (threadIdx.x == 0 && blockIdx.x == 0) {
        float l0 = -acc[0], l1 = -acc[1], ls = -acc[2];
        float s0 = *sd0p, s1 = *sd1p, ss = *sdqp;
        float tf = l0 / (s0 * s0 + EPSF) + 400000.f * logf(s0 + EPSF)
                 + l1 / (s1 * s1 + EPSF) + 400000.f * logf(s1 + EPSF)
                 + ls / (ss * ss + EPSF) + 512.f * logf(ss + EPSF);
        out[0] = tf;
    }
}

extern "C" void kernel_launch(void* const* d_in, const int* in_sizes, int n_in,
                              void* d_out, int out_size, void* d_ws, size_t ws_size,
                              hipStream_t stream) {
    const float* emb   = (const float*)d_in[0];
    const float* Wrep  = (const float*)d_in[1];
    const float* Wq    = (const float*)d_in[2];
    const float* Wk    = (const float*)d_in[3];
    const float* Wv    = (const float*)d_in[4];
    const float* Hd    = (const float*)d_in[5];
    const float* uinit = (const float*)d_in[6];
    const float* sd0   = (const float*)d_in[7];
    const float* sd1   = (const float*)d_in[8];
    const float* sdq   = (const float*)d_in[9];
    const int* pe0 = (const int*)d_in[10];
    const int* ne0 = (const int*)d_in[11];
    const int* pe1 = (const int*)d_in[12];
    const int* ne1 = (const int*)d_in[13];
    const int* qs  = (const int*)d_in[14];
    const int* cs  = (const int*)d_in[15];

    float* ws = (float*)d_ws;
    float* acc = ws;                 // 16 floats (3 used)
    const size_t SZ = (size_t)BB * LL * DD;   // 4,194,304 floats
    float* QT  = ws + 16;
    float* KT  = QT + SZ;
    float* VT  = KT + SZ;
    float* BvT = VT + SZ;
    float* OT  = BvT + SZ;           // total ~84 MB

    hipMemsetAsync(acc, 0, 16 * sizeof(float), stream);

    edge0_kernel<<<1024, 256, 0, stream>>>(emb, pe0, ne0, acc);
    edge1_kernel<<<1024, 256, 0, stream>>>(emb, pe1, ne1, acc);

    proj_kernel<<<dim3(16, 3, 64), 256, 0, stream>>>(emb, Wrep, Wq, Wk, Wv,
                                                     qs, cs, QT, KT, VT);
    attn_mfma_kernel<<<512, 256, 0, stream>>>(QT, KT, VT, BvT);
    head_kernel<<<dim3(16, 64), 256, 0, stream>>>(Hd, BvT, OT);
    pred_kernel<<<512, 256, 0, stream>>>(OT, emb, uinit, qs, cs, acc);

    combine_kernel<<<1, 64, 0, stream>>>(acc, sd0, sd1, sdq, (float*)d_out);
}

// Round 4
// 254.412 us; speedup vs baseline: 5.9034x; 1.4521x over previous
//
#include <hip/hip_runtime.h>
#include <hip/hip_bf16.h>

#define EPSF 1e-8f
#define NN 50000
#define DD 128
#define BB 64
#define LL 512
#define PP0 200000
#define PP1 50000
#define SCALE 0.08838834764831845f  // 1/sqrt(128)

typedef float f4v __attribute__((ext_vector_type(4)));
typedef short s8v __attribute__((ext_vector_type(8)));
typedef short s4v __attribute__((ext_vector_type(4)));

__device__ __forceinline__ float logsigf(float x) {
    float s = 1.f / (1.f + __expf(-x));
    return __logf(s + EPSF);
}

__device__ __forceinline__ float red64(float v) {
    #pragma unroll
    for (int m = 32; m >= 1; m >>= 1) v += __shfl_xor(v, m, 64);
    return v;
}

__device__ __forceinline__ void block_atomic_sum(float local, float* dst) {
    local = red64(local);
    __shared__ float w4[4];
    if ((threadIdx.x & 63) == 0) w4[threadIdx.x >> 6] = local;
    __syncthreads();
    if (threadIdx.x == 0) atomicAdd(dst, w4[0] + w4[1] + w4[2] + w4[3]);
}

// float -> bf16 bits (round-to-nearest-even)
__device__ __forceinline__ unsigned short f2bf(float f) {
    unsigned u = __float_as_uint(f);
    unsigned r = (u + 0x7fffu + ((u >> 16) & 1u)) >> 16;
    return (unsigned short)r;
}
__device__ __forceinline__ float bf2f(unsigned short u) {
    return __uint_as_float(((unsigned)u) << 16);
}

__device__ __forceinline__ float dot8bf(s8v a, s8v b) {
    float s = 0.f;
    #pragma unroll
    for (int j = 0; j < 8; j++)
        s += bf2f((unsigned short)a[j]) * bf2f((unsigned short)b[j]);
    return s;
}

// ---------------- one-shot converts -----------------------------------------
__global__ __launch_bounds__(256) void cvt_emb_kernel(
    const float* __restrict__ emb, unsigned short* __restrict__ emb16)
{
    int stride = gridDim.x * 256 * 8;
    for (int i = (blockIdx.x * 256 + threadIdx.x) * 8; i < NN * DD; i += stride) {
        float4 a = *(const float4*)&emb[i];
        float4 b = *(const float4*)&emb[i + 4];
        s8v o;
        o[0] = (short)f2bf(a.x); o[1] = (short)f2bf(a.y);
        o[2] = (short)f2bf(a.z); o[3] = (short)f2bf(a.w);
        o[4] = (short)f2bf(b.x); o[5] = (short)f2bf(b.y);
        o[6] = (short)f2bf(b.z); o[7] = (short)f2bf(b.w);
        *(s8v*)&emb16[i] = o;
    }
}

// Wq|Wk|Wv|Head_agg -> W16[4][128*128] bf16. grid 32x256 exactly covers it.
__global__ __launch_bounds__(256) void cvt_w_kernel(
    const float* __restrict__ Wq, const float* __restrict__ Wk,
    const float* __restrict__ Wv, const float* __restrict__ Hd,
    unsigned short* __restrict__ W16)
{
    int idx = (blockIdx.x * 256 + threadIdx.x) * 8;
    int which = idx >> 14, off = idx & 16383;
    const float* src = (which == 0) ? Wq : (which == 1) ? Wk : (which == 2) ? Wv : Hd;
    float4 a = *(const float4*)&src[off];
    float4 b = *(const float4*)&src[off + 4];
    s8v o;
    o[0] = (short)f2bf(a.x); o[1] = (short)f2bf(a.y);
    o[2] = (short)f2bf(a.z); o[3] = (short)f2bf(a.w);
    o[4] = (short)f2bf(b.x); o[5] = (short)f2bf(b.y);
    o[6] = (short)f2bf(b.z); o[7] = (short)f2bf(b.w);
    *(s8v*)&W16[idx] = o;
}

// ---------------- Edge task 0: 16 lanes per pair, bf16 rows -----------------
__global__ __launch_bounds__(256) void edge0_kernel(
    const unsigned short* __restrict__ emb16, const int* __restrict__ pos,
    const int* __restrict__ neg, float* __restrict__ acc)
{
    int sub = threadIdx.x & 15;
    int g0 = (blockIdx.x * 256 + threadIdx.x) >> 4;
    int ng = gridDim.x * 16;
    float local = 0.f;
    for (int grp = g0; grp < 2 * PP0; grp += ng) {
        bool isneg = grp >= PP0;
        const int* e = isneg ? (neg + 2 * (grp - PP0)) : (pos + 2 * grp);
        int h = e[0], t = e[1];
        s8v a = *(const s8v*)&emb16[(size_t)h * DD + 8 * sub];
        s8v b = *(const s8v*)&emb16[(size_t)t * DD + 8 * sub];
        float d = dot8bf(a, b);
        #pragma unroll
        for (int m = 8; m >= 1; m >>= 1) d += __shfl_xor(d, m, 64);
        if (sub == 0) local += logsigf(isneg ? -d : d);
    }
    block_atomic_sum(local, acc);
}

// ---------------- Edge task 1: 16 lanes per i, pos pair reused x4 -----------
__global__ __launch_bounds__(256) void edge1_kernel(
    const unsigned short* __restrict__ emb16, const int* __restrict__ pos1,
    const int* __restrict__ neg1, float* __restrict__ acc)
{
    int sub = threadIdx.x & 15;
    int g0 = (blockIdx.x * 256 + threadIdx.x) >> 4;
    int ng = gridDim.x * 16;
    float local = 0.f;
    for (int i = g0; i < PP1; i += ng) {
        int ph = pos1[2 * i], pt = pos1[2 * i + 1];
        s8v vph = *(const s8v*)&emb16[(size_t)ph * DD + 8 * sub];
        s8v vpt = *(const s8v*)&emb16[(size_t)pt * DD + 8 * sub];
        float ps = dot8bf(vph, vpt);
        #pragma unroll
        for (int m = 8; m >= 1; m >>= 1) ps += __shfl_xor(ps, m, 64);
        #pragma unroll
        for (int mloop = 0; mloop < 4; mloop++) {
            int g = mloop * PP1 + i;
            int nh = neg1[2 * g], nt = neg1[2 * g + 1];
            s8v vnh = *(const s8v*)&emb16[(size_t)nh * DD + 8 * sub];
            s8v vnt = *(const s8v*)&emb16[(size_t)nt * DD + 8 * sub];
            float sh = dot8bf(vnh, vpt);
            float st = dot8bf(vph, vnt);
            #pragma unroll
            for (int m = 8; m >= 1; m >>= 1) sh += __shfl_xor(sh, m, 64);
            #pragma unroll
            for (int m = 8; m >= 1; m >>= 1) st += __shfl_xor(st, m, 64);
            if (sub == 0) local += logsigf(ps - sh) + logsigf(ps - st);
        }
    }
    block_atomic_sum(local, acc + 1);
}

// ---------------- QKV projection, bf16 MFMA ---------------------------------
// grid (8 t-tiles of 64, 64 users). C[r][t] = W[r][:] . I[t][:]; out^T bf16.
__global__ __launch_bounds__(256) void proj_kernel(
    const unsigned short* __restrict__ emb16, const float* __restrict__ Wrep,
    const unsigned short* __restrict__ W16, const int* __restrict__ qseq,
    const int* __restrict__ cseq, unsigned short* __restrict__ QT16,
    unsigned short* __restrict__ KT16, unsigned short* __restrict__ VT16)
{
    int b = blockIdx.y;
    int t0 = blockIdx.x * 64;
    __shared__ unsigned short Itok[64 * 136];
    __shared__ unsigned short Wl[128 * 136];
    __shared__ int qs[64];
    __shared__ int cs[64];
    int tid = threadIdx.x;
    if (tid < 64) {
        qs[tid] = qseq[b * LL + t0 + tid];
        cs[tid] = cseq[b * LL + t0 + tid];
    }
    __syncthreads();
    {   // stage I[t][d] = emb[qs[t]][d] + Wrep[d][cs[t]] as bf16
        int t = tid >> 2, d0 = (tid & 3) * 32;
        const unsigned short* er = emb16 + (size_t)qs[t] * DD + d0;
        int c = cs[t];
        #pragma unroll
        for (int e = 0; e < 32; e += 8) {
            s8v raw = *(const s8v*)&er[e];
            s8v o;
            #pragma unroll
            for (int j = 0; j < 8; j++) {
                float f = bf2f((unsigned short)raw[j]) + Wrep[(d0 + e + j) * 2 + c];
                o[j] = (short)f2bf(f);
            }
            *(s8v*)&Itok[t * 136 + d0 + e] = o;
        }
    }
    int w = tid >> 6, lane = tid & 63, n = lane & 15, quad = lane >> 4;

    for (int w3 = 0; w3 < 3; w3++) {
        __syncthreads();   // Itok ready / previous waves done reading Wl
        {   // stage W[w3] (bf16 copy, no conversion)
            const unsigned short* src = W16 + w3 * DD * DD + (tid >> 1) * DD + (tid & 1) * 64;
            unsigned short* dst = &Wl[(tid >> 1) * 136 + (tid & 1) * 64];
            #pragma unroll
            for (int e = 0; e < 64; e += 8)
                *(s8v*)&dst[e] = *(const s8v*)&src[e];
        }
        __syncthreads();
        f4v a2[2][4];
        #pragma unroll
        for (int mt = 0; mt < 2; mt++)
            #pragma unroll
            for (int nt = 0; nt < 4; nt++) a2[mt][nt] = (f4v){0.f, 0.f, 0.f, 0.f};
        #pragma unroll
        for (int c = 0; c < 4; c++) {
            s8v af0 = *(const s8v*)&Wl[(w * 32 + n) * 136 + c * 32 + quad * 8];
            s8v af1 = *(const s8v*)&Wl[(w * 32 + 16 + n) * 136 + c * 32 + quad * 8];
            #pragma unroll
            for (int nt = 0; nt < 4; nt++) {
                s8v bf = *(const s8v*)&Itok[(nt * 16 + n) * 136 + c * 32 + quad * 8];
                a2[0][nt] = __builtin_amdgcn_mfma_f32_16x16x32_bf16(af0, bf, a2[0][nt], 0, 0, 0);
                a2[1][nt] = __builtin_amdgcn_mfma_f32_16x16x32_bf16(af1, bf, a2[1][nt], 0, 0, 0);
            }
        }
        unsigned short* OUT = (w3 == 0) ? QT16 : (w3 == 1) ? KT16 : VT16;
        #pragma unroll
        for (int mt = 0; mt < 2; mt++)
            #pragma unroll
            for (int nt = 0; nt < 4; nt++) {
                int t = t0 + nt * 16 + n;
                int r = w * 32 + mt * 16 + quad * 4;
                s4v o;
                #pragma unroll
                for (int rr = 0; rr < 4; rr++) o[rr] = (short)f2bf(a2[mt][nt][rr]);
                *(s4v*)&OUT[((size_t)(b * LL) + t) * DD + r] = o;
            }
    }
}

// ---------------- Flash attention, bf16 MFMA (bf16 Q/K/V inputs) ------------
__global__ __launch_bounds__(256) void attn_mfma_kernel(
    const unsigned short* __restrict__ QT16, const unsigned short* __restrict__ KT16,
    const unsigned short* __restrict__ VT16, float* __restrict__ BvT)
{
    int id = blockIdx.x;
    int r0 = id & 255;
    int b = r0 & 63;
    int qt = (id >> 8) ? (7 - (r0 >> 6)) : (r0 >> 6);

    __shared__ unsigned short K_lds[64 * 136];   // [key][d]
    __shared__ unsigned short Vt_lds[128 * 72];  // [d][key]
    __shared__ unsigned short P_lds[64 * 72];    // [query][key]

    int tid = threadIdx.x;
    int w = tid >> 6;
    int lane = tid & 63;
    int n = lane & 15;
    int quad = lane >> 4;
    int gj = qt * 64 + w * 16 + n;

    // Q fragments direct from bf16 global
    s8v qfrag[4];
    {
        const unsigned short* qrow = QT16 + ((size_t)(b * LL) + gj) * DD;
        #pragma unroll
        for (int c = 0; c < 4; c++)
            qfrag[c] = *(const s8v*)&qrow[c * 32 + quad * 8];
    }

    f4v oacc[8];
    #pragma unroll
    for (int dt = 0; dt < 8; dt++) oacc[dt] = (f4v){0.f, 0.f, 0.f, 0.f};
    float m_run = -INFINITY, l_run = 0.f;

    for (int kt = 0; kt <= qt; ++kt) {
        __syncthreads();
        #pragma unroll
        for (int rep = 0; rep < 4; rep++) {
            int idx = rep * 2048 + tid * 8;
            int i = idx >> 7, d = idx & 127;
            size_t g = ((size_t)(b * LL) + kt * 64 + i) * DD + d;
            s8v kb = *(const s8v*)&KT16[g];
            s8v vb = *(const s8v*)&VT16[g];
            *(s8v*)&K_lds[i * 136 + d] = kb;
            #pragma unroll
            for (int e = 0; e < 8; e++)
                Vt_lds[(d + e) * 72 + i] = (unsigned short)vb[e];
        }
        __syncthreads();

        f4v sacc[4];
        #pragma unroll
        for (int mt = 0; mt < 4; mt++) sacc[mt] = (f4v){0.f, 0.f, 0.f, 0.f};
        #pragma unroll
        for (int c = 0; c < 4; c++) {
            #pragma unroll
            for (int mt = 0; mt < 4; mt++) {
                s8v af = *(const s8v*)&K_lds[(mt * 16 + n) * 136 + c * 32 + quad * 8];
                sacc[mt] = __builtin_amdgcn_mfma_f32_16x16x32_bf16(af, qfrag[c], sacc[mt], 0, 0, 0);
            }
        }

        bool diag = (kt == qt);
        float mloc = -INFINITY;
        #pragma unroll
        for (int mt = 0; mt < 4; mt++) {
            #pragma unroll
            for (int rr = 0; rr < 4; rr++) {
                float s = sacc[mt][rr] * SCALE;
                if (diag && (kt * 64 + mt * 16 + quad * 4 + rr) > gj) s = -INFINITY;
                sacc[mt][rr] = s;
                mloc = fmaxf(mloc, s);
            }
        }
        mloc = fmaxf(mloc, __shfl_xor(mloc, 16));
        mloc = fmaxf(mloc, __shfl_xor(mloc, 32));
        float mnew = fmaxf(m_run, mloc);
        float alpha = __expf(m_run - mnew);
        m_run = mnew;

        float rsum = 0.f;
        #pragma unroll
        for (int mt = 0; mt < 4; mt++) {
            s4v pp;
            #pragma unroll
            for (int rr = 0; rr < 4; rr++) {
                float p = __expf(sacc[mt][rr] - mnew);
                rsum += p;
                pp[rr] = (short)f2bf(p);
            }
            *(s4v*)&P_lds[(w * 16 + n) * 72 + mt * 16 + quad * 4] = pp;
        }
        rsum += __shfl_xor(rsum, 16);
        rsum += __shfl_xor(rsum, 32);
        l_run = l_run * alpha + rsum;

        #pragma unroll
        for (int rr = 0; rr < 4; rr++) {
            float a_r = __shfl(alpha, quad * 4 + rr);
            #pragma unroll
            for (int dt = 0; dt < 8; dt++) oacc[dt][rr] *= a_r;
        }

        #pragma unroll
        for (int cc = 0; cc < 2; cc++) {
            s8v pf = *(const s8v*)&P_lds[(w * 16 + n) * 72 + cc * 32 + quad * 8];
            #pragma unroll
            for (int dt = 0; dt < 8; dt++) {
                s8v vf = *(const s8v*)&Vt_lds[(dt * 16 + n) * 72 + cc * 32 + quad * 8];
                oacc[dt] = __builtin_amdgcn_mfma_f32_16x16x32_bf16(pf, vf, oacc[dt], 0, 0, 0);
            }
        }
    }

    float linv = 1.f / l_run;
    #pragma unroll
    for (int rr = 0; rr < 4; rr++) {
        float li = __shfl(linv, quad * 4 + rr);
        int t = qt * 64 + w * 16 + quad * 4 + rr;
        float* orow = BvT + ((size_t)(b * LL) + t) * DD;
        #pragma unroll
        for (int dt = 0; dt < 8; dt++)
            orow[dt * 16 + n] = oacc[dt][rr] * li;
    }
}

// ---------------- O = Head_agg @ Bv, bf16 MFMA, fp32 out --------------------
__global__ __launch_bounds__(256) void head_kernel(
    const unsigned short* __restrict__ H16, const float* __restrict__ BvT,
    float* __restrict__ OT)
{
    int b = blockIdx.y;
    int t0 = blockIdx.x * 64;
    __shared__ unsigned short Btok[64 * 136];
    __shared__ unsigned short Hl[128 * 136];
    int tid = threadIdx.x;
    {
        int t = tid >> 2, d0 = (tid & 3) * 32;
        const float* br = BvT + ((size_t)(b * LL) + t0 + t) * DD + d0;
        #pragma unroll
        for (int e = 0; e < 32; e += 8) {
            float4 x = *(const float4*)&br[e];
            float4 y = *(const float4*)&br[e + 4];
            s8v o;
            o[0] = (short)f2bf(x.x); o[1] = (short)f2bf(x.y);
            o[2] = (short)f2bf(x.z); o[3] = (short)f2bf(x.w);
            o[4] = (short)f2bf(y.x); o[5] = (short)f2bf(y.y);
            o[6] = (short)f2bf(y.z); o[7] = (short)f2bf(y.w);
            *(s8v*)&Btok[t * 136 + d0 + e] = o;
        }
    }
    {
        const unsigned short* src = H16 + (tid >> 1) * DD + (tid & 1) * 64;
        unsigned short* dst = &Hl[(tid >> 1) * 136 + (tid & 1) * 64];
        #pragma unroll
        for (int e = 0; e < 64; e += 8)
            *(s8v*)&dst[e] = *(const s8v*)&src[e];
    }
    __syncthreads();

    int w = tid >> 6, lane = tid & 63, n = lane & 15, quad = lane >> 4;
    f4v a2[2][4];
    #pragma unroll
    for (int mt = 0; mt < 2; mt++)
        #pragma unroll
        for (int nt = 0; nt < 4; nt++) a2[mt][nt] = (f4v){0.f, 0.f, 0.f, 0.f};
    #pragma unroll
    for (int c = 0; c < 4; c++) {
        s8v af0 = *(const s8v*)&Hl[(w * 32 + n) * 136 + c * 32 + quad * 8];
        s8v af1 = *(const s8v*)&Hl[(w * 32 + 16 + n) * 136 + c * 32 + quad * 8];
        #pragma unroll
        for (int nt = 0; nt < 4; nt++) {
            s8v bf = *(const s8v*)&Btok[(nt * 16 + n) * 136 + c * 32 + quad * 8];
            a2[0][nt] = __builtin_amdgcn_mfma_f32_16x16x32_bf16(af0, bf, a2[0][nt], 0, 0, 0);
            a2[1][nt] = __builtin_amdgcn_mfma_f32_16x16x32_bf16(af1, bf, a2[1][nt], 0, 0, 0);
        }
    }
    #pragma unroll
    for (int mt = 0; mt < 2; mt++)
        #pragma unroll
        for (int nt = 0; nt < 4; nt++) {
            int t = t0 + nt * 16 + n;
            int r = w * 32 + mt * 16 + quad * 4;
            *(float4*)&OT[((size_t)(b * LL) + t) * DD + r] =
                make_float4(a2[mt][nt][0], a2[mt][nt][1], a2[mt][nt][2], a2[mt][nt][3]);
        }
}

// ---------------- prediction loss: grid-stride, 32 lanes per (b,t) ----------
__global__ __launch_bounds__(256) void pred_kernel(
    const float* __restrict__ OT, const float* __restrict__ emb,
    const float* __restrict__ uinit, const int* __restrict__ qseq,
    const int* __restrict__ cseq, float* __restrict__ acc)
{
    int sub = threadIdx.x & 31;
    int half = (blockIdx.x * 256 + threadIdx.x) >> 5;
    int nhalf = gridDim.x * 8;
    float local = 0.f;
    for (int grp = half; grp < BB * LL; grp += nhalf) {
        int b = grp >> 9;
        int t = grp & 511;
        const float* u = (t == 0) ? uinit : (OT + ((size_t)b * LL + (t - 1)) * DD);
        int qi = qseq[b * LL + t];
        float4 uv = ((const float4*)u)[sub];
        float4 ev = ((const float4*)(emb + (size_t)qi * DD))[sub];
        float s = uv.x * ev.x + uv.y * ev.y + uv.z * ev.z + uv.w * ev.w;
        #pragma unroll
        for (int m = 16; m >= 1; m >>= 1) s += __shfl_xor(s, m, 64);
        if (sub == 0) {
            float c = (float)cseq[b * LL + t];
            float pred = 1.f / (1.f + __expf(-s));
            local += c * __logf(pred + EPSF) + (1.f - c) * __logf(1.f - pred + EPSF);
        }
    }
    block_atomic_sum(local, acc + 2);
}

// ---------------- final combine ---------------------------------------------
__global__ void combine_kernel(
    const float* __restrict__ acc, const float* __restrict__ sd0p,
    const float* __restrict__ sd1p, const float* __restrict__ sdqp,
    float* __restrict__ out)
{
    if (threadIdx.x == 0 && blockIdx.x == 0) {
        float l0 = -acc[0], l1 = -acc[1], ls = -acc[2];
        float s0 = *sd0p, s1 = *sd1p, ss = *sdqp;
        float tf = l0 / (s0 * s0 + EPSF) + 400000.f * logf(s0 + EPSF)
                 + l1 / (s1 * s1 + EPSF) + 400000.f * logf(s1 + EPSF)
                 + ls / (ss * ss + EPSF) + 512.f * logf(ss + EPSF);
        out[0] = tf;
    }
}

extern "C" void kernel_launch(void* const* d_in, const int* in_sizes, int n_in,
                              void* d_out, int out_size, void* d_ws, size_t ws_size,
                              hipStream_t stream) {
    const float* emb   = (const float*)d_in[0];
    const float* Wrep  = (const float*)d_in[1];
    const float* Wq    = (const float*)d_in[2];
    const float* Wk    = (const float*)d_in[3];
    const float* Wv    = (const float*)d_in[4];
    const float* Hd    = (const float*)d_in[5];
    const float* uinit = (const float*)d_in[6];
    const float* sd0   = (const float*)d_in[7];
    const float* sd1   = (const float*)d_in[8];
    const float* sdq   = (const float*)d_in[9];
    const int* pe0 = (const int*)d_in[10];
    const int* ne0 = (const int*)d_in[11];
    const int* pe1 = (const int*)d_in[12];
    const int* ne1 = (const int*)d_in[13];
    const int* qs  = (const int*)d_in[14];
    const int* cs  = (const int*)d_in[15];

    const size_t SZ = (size_t)BB * LL * DD;   // 4,194,304
    char* base = (char*)d_ws;
    float* acc = (float*)base;                                  // 256 B
    unsigned short* emb16 = (unsigned short*)(base + 256);      // 12.8 MB
    unsigned short* W16   = emb16 + (size_t)NN * DD;            // 128 KB (Wq,Wk,Wv,H)
    unsigned short* QT16  = W16 + 4 * DD * DD;
    unsigned short* KT16  = QT16 + SZ;
    unsigned short* VT16  = KT16 + SZ;
    float* BvT = (float*)(VT16 + SZ);
    float* OT  = BvT + SZ;                                      // total ~71.7 MB

    hipMemsetAsync(acc, 0, 256, stream);

    cvt_emb_kernel<<<1024, 256, 0, stream>>>(emb, emb16);
    cvt_w_kernel<<<32, 256, 0, stream>>>(Wq, Wk, Wv, Hd, W16);

    edge0_kernel<<<1024, 256, 0, stream>>>(emb16, pe0, ne0, acc);
    edge1_kernel<<<1024, 256, 0, stream>>>(emb16, pe1, ne1, acc);

    proj_kernel<<<dim3(8, 64), 256, 0, stream>>>(emb16, Wrep, W16, qs, cs,
                                                 QT16, KT16, VT16);
    attn_mfma_kernel<<<512, 256, 0, stream>>>(QT16, KT16, VT16, BvT);
    head_kernel<<<dim3(8, 64), 256, 0, stream>>>(W16 + 3 * DD * DD, BvT, OT);
    pred_kernel<<<512, 256, 0, stream>>>(OT, emb, uinit, qs, cs, acc);

    combine_kernel<<<1, 64, 0, stream>>>(acc, sd0, sd1, sdq, (float*)d_out);
}

// Round 5
// 214.800 us; speedup vs baseline: 6.9921x; 1.1844x over previous
//
#include <hip/hip_runtime.h>
#include <hip/hip_bf16.h>

#define EPSF 1e-8f
#define NN 50000
#define DD 128
#define BB 64
#define LL 512
#define PP0 200000
#define PP1 50000
#define SCALE 0.08838834764831845f  // 1/sqrt(128)

typedef float f4v __attribute__((ext_vector_type(4)));
typedef short s8v __attribute__((ext_vector_type(8)));
typedef short s4v __attribute__((ext_vector_type(4)));

__device__ __forceinline__ float logsigf(float x) {
    float s = 1.f / (1.f + __expf(-x));
    return __logf(s + EPSF);
}

__device__ __forceinline__ float red64(float v) {
    #pragma unroll
    for (int m = 32; m >= 1; m >>= 1) v += __shfl_xor(v, m, 64);
    return v;
}
__device__ __forceinline__ float red16(float v) {
    #pragma unroll
    for (int m = 8; m >= 1; m >>= 1) v += __shfl_xor(v, m, 64);
    return v;
}

__device__ __forceinline__ void block_atomic_sum(float local, float* dst) {
    local = red64(local);
    __shared__ float w4[4];
    if ((threadIdx.x & 63) == 0) w4[threadIdx.x >> 6] = local;
    __syncthreads();
    if (threadIdx.x == 0) atomicAdd(dst, w4[0] + w4[1] + w4[2] + w4[3]);
}

// float -> bf16 bits (round-to-nearest-even)
__device__ __forceinline__ unsigned short f2bf(float f) {
    unsigned u = __float_as_uint(f);
    unsigned r = (u + 0x7fffu + ((u >> 16) & 1u)) >> 16;
    return (unsigned short)r;
}
__device__ __forceinline__ float bf2f(unsigned short u) {
    return __uint_as_float(((unsigned)u) << 16);
}

__device__ __forceinline__ float dot8bf(s8v a, s8v b) {
    float s = 0.f;
    #pragma unroll
    for (int j = 0; j < 8; j++)
        s += bf2f((unsigned short)a[j]) * bf2f((unsigned short)b[j]);
    return s;
}

// ---------------- one-shot converts -----------------------------------------
__global__ __launch_bounds__(256) void cvt_emb_kernel(
    const float* __restrict__ emb, unsigned short* __restrict__ emb16)
{
    int stride = gridDim.x * 256 * 8;
    for (int i = (blockIdx.x * 256 + threadIdx.x) * 8; i < NN * DD; i += stride) {
        float4 a = *(const float4*)&emb[i];
        float4 b = *(const float4*)&emb[i + 4];
        s8v o;
        o[0] = (short)f2bf(a.x); o[1] = (short)f2bf(a.y);
        o[2] = (short)f2bf(a.z); o[3] = (short)f2bf(a.w);
        o[4] = (short)f2bf(b.x); o[5] = (short)f2bf(b.y);
        o[6] = (short)f2bf(b.z); o[7] = (short)f2bf(b.w);
        *(s8v*)&emb16[i] = o;
    }
}

__global__ __launch_bounds__(256) void cvt_w_kernel(
    const float* __restrict__ Wq, const float* __restrict__ Wk,
    const float* __restrict__ Wv, const float* __restrict__ Hd,
    unsigned short* __restrict__ W16)
{
    int idx = (blockIdx.x * 256 + threadIdx.x) * 8;
    int which = idx >> 14, off = idx & 16383;
    const float* src = (which == 0) ? Wq : (which == 1) ? Wk : (which == 2) ? Wv : Hd;
    float4 a = *(const float4*)&src[off];
    float4 b = *(const float4*)&src[off + 4];
    s8v o;
    o[0] = (short)f2bf(a.x); o[1] = (short)f2bf(a.y);
    o[2] = (short)f2bf(a.z); o[3] = (short)f2bf(a.w);
    o[4] = (short)f2bf(b.x); o[5] = (short)f2bf(b.y);
    o[6] = (short)f2bf(b.z); o[7] = (short)f2bf(b.w);
    *(s8v*)&W16[idx] = o;
}

// ---------------- Edge tasks fused: blocks [0,1024)=e0, [1024,1536)=e1 ------
__global__ __launch_bounds__(256) void edges_kernel(
    const unsigned short* __restrict__ emb16, const int* __restrict__ pos,
    const int* __restrict__ neg, const int* __restrict__ pos1,
    const int* __restrict__ neg1, float* __restrict__ acc)
{
    int sub = threadIdx.x & 15;
    if (blockIdx.x < 1024) {
        int g0 = (blockIdx.x * 256 + threadIdx.x) >> 4;
        int ng = 1024 * 16;
        float local = 0.f;
        for (int grp = g0; grp < 2 * PP0; grp += ng) {
            bool isneg = grp >= PP0;
            const int* e = isneg ? (neg + 2 * (grp - PP0)) : (pos + 2 * grp);
            int h = e[0], t = e[1];
            s8v a = *(const s8v*)&emb16[(size_t)h * DD + 8 * sub];
            s8v b = *(const s8v*)&emb16[(size_t)t * DD + 8 * sub];
            float d = red16(dot8bf(a, b));
            if (sub == 0) local += logsigf(isneg ? -d : d);
        }
        block_atomic_sum(local, acc);
    } else {
        int g0 = ((blockIdx.x - 1024) * 256 + threadIdx.x) >> 4;
        int ng = 512 * 16;
        float local = 0.f;
        for (int i = g0; i < PP1; i += ng) {
            int ph = pos1[2 * i], pt = pos1[2 * i + 1];
            s8v vph = *(const s8v*)&emb16[(size_t)ph * DD + 8 * sub];
            s8v vpt = *(const s8v*)&emb16[(size_t)pt * DD + 8 * sub];
            float ps = red16(dot8bf(vph, vpt));
            #pragma unroll
            for (int mloop = 0; mloop < 4; mloop++) {
                int g = mloop * PP1 + i;
                int nh = neg1[2 * g], nt = neg1[2 * g + 1];
                s8v vnh = *(const s8v*)&emb16[(size_t)nh * DD + 8 * sub];
                s8v vnt = *(const s8v*)&emb16[(size_t)nt * DD + 8 * sub];
                float sh = red16(dot8bf(vnh, vpt));
                float st = red16(dot8bf(vph, vnt));
                if (sub == 0) local += logsigf(ps - sh) + logsigf(ps - st);
            }
        }
        block_atomic_sum(local, acc + 1);
    }
}

// ---------------- QKV projection, bf16 MFMA ---------------------------------
// Q,K row-major [b*L+t][d]; V written TRANSPOSED: VT16T[b][d=0..127][key=0..511]
__global__ __launch_bounds__(256) void proj_kernel(
    const unsigned short* __restrict__ emb16, const float* __restrict__ Wrep,
    const unsigned short* __restrict__ W16, const int* __restrict__ qseq,
    const int* __restrict__ cseq, unsigned short* __restrict__ QT16,
    unsigned short* __restrict__ KT16, unsigned short* __restrict__ VT16T)
{
    int b = blockIdx.y;
    int t0 = blockIdx.x * 64;
    __shared__ unsigned short Itok[64 * 136];
    __shared__ unsigned short Wl[128 * 136];   // reused as V^T[r][t] stride 72 in epilogue
    __shared__ int qs[64];
    __shared__ int cs[64];
    int tid = threadIdx.x;
    if (tid < 64) {
        qs[tid] = qseq[b * LL + t0 + tid];
        cs[tid] = cseq[b * LL + t0 + tid];
    }
    __syncthreads();
    {   // stage I[t][d] = emb[qs[t]][d] + Wrep[d][cs[t]] as bf16
        int t = tid >> 2, d0 = (tid & 3) * 32;
        const unsigned short* er = emb16 + (size_t)qs[t] * DD + d0;
        int c = cs[t];
        #pragma unroll
        for (int e = 0; e < 32; e += 8) {
            s8v raw = *(const s8v*)&er[e];
            s8v o;
            #pragma unroll
            for (int j = 0; j < 8; j++) {
                float f = bf2f((unsigned short)raw[j]) + Wrep[(d0 + e + j) * 2 + c];
                o[j] = (short)f2bf(f);
            }
            *(s8v*)&Itok[t * 136 + d0 + e] = o;
        }
    }
    int w = tid >> 6, lane = tid & 63, n = lane & 15, quad = lane >> 4;

    for (int w3 = 0; w3 < 3; w3++) {
        __syncthreads();
        {   // stage W[w3]
            const unsigned short* src = W16 + w3 * DD * DD + (tid >> 1) * DD + (tid & 1) * 64;
            unsigned short* dst = &Wl[(tid >> 1) * 136 + (tid & 1) * 64];
            #pragma unroll
            for (int e = 0; e < 64; e += 8)
                *(s8v*)&dst[e] = *(const s8v*)&src[e];
        }
        __syncthreads();
        f4v a2[2][4];
        #pragma unroll
        for (int mt = 0; mt < 2; mt++)
            #pragma unroll
            for (int nt = 0; nt < 4; nt++) a2[mt][nt] = (f4v){0.f, 0.f, 0.f, 0.f};
        #pragma unroll
        for (int c = 0; c < 4; c++) {
            s8v af0 = *(const s8v*)&Wl[(w * 32 + n) * 136 + c * 32 + quad * 8];
            s8v af1 = *(const s8v*)&Wl[(w * 32 + 16 + n) * 136 + c * 32 + quad * 8];
            #pragma unroll
            for (int nt = 0; nt < 4; nt++) {
                s8v bf = *(const s8v*)&Itok[(nt * 16 + n) * 136 + c * 32 + quad * 8];
                a2[0][nt] = __builtin_amdgcn_mfma_f32_16x16x32_bf16(af0, bf, a2[0][nt], 0, 0, 0);
                a2[1][nt] = __builtin_amdgcn_mfma_f32_16x16x32_bf16(af1, bf, a2[1][nt], 0, 0, 0);
            }
        }
        if (w3 < 2) {
            unsigned short* OUT = (w3 == 0) ? QT16 : KT16;
            #pragma unroll
            for (int mt = 0; mt < 2; mt++)
                #pragma unroll
                for (int nt = 0; nt < 4; nt++) {
                    int t = t0 + nt * 16 + n;
                    int r = w * 32 + mt * 16 + quad * 4;
                    s4v o;
                    #pragma unroll
                    for (int rr = 0; rr < 4; rr++) o[rr] = (short)f2bf(a2[mt][nt][rr]);
                    *(s4v*)&OUT[((size_t)(b * LL) + t) * DD + r] = o;
                }
        } else {
            // V: scatter into LDS [r][t] stride 72 (144 B, 16-aligned), then
            // coalesced b128 store of V^T rows to global.
            __syncthreads();   // all waves done reading Wl
            #pragma unroll
            for (int mt = 0; mt < 2; mt++)
                #pragma unroll
                for (int nt = 0; nt < 4; nt++) {
                    int tl = nt * 16 + n;
                    int r = w * 32 + mt * 16 + quad * 4;
                    #pragma unroll
                    for (int rr = 0; rr < 4; rr++)
                        Wl[(r + rr) * 72 + tl] = f2bf(a2[mt][nt][rr]);
                }
            __syncthreads();
            int row = tid >> 1, half = tid & 1;
            unsigned short* gdst = VT16T + ((size_t)b * DD + row) * LL + t0 + half * 32;
            const unsigned short* lsrc = &Wl[row * 72 + half * 32];
            #pragma unroll
            for (int e = 0; e < 32; e += 8)
                *(s8v*)&gdst[e] = *(const s8v*)&lsrc[e];
        }
    }
}

// ---------------- Flash attention, bf16 MFMA, pipelined staging -------------
__global__ __launch_bounds__(256) void attn_mfma_kernel(
    const unsigned short* __restrict__ QT16, const unsigned short* __restrict__ KT16,
    const unsigned short* __restrict__ VT16T, float* __restrict__ BvT)
{
    int id = blockIdx.x;
    int r0 = id & 255;
    int b = r0 & 63;
    int qt = (id >> 8) ? (7 - (r0 >> 6)) : (r0 >> 6);

    __shared__ unsigned short K_lds[64 * 136];   // [key][d]
    __shared__ unsigned short Vt_lds[128 * 72];  // [d][key]
    __shared__ unsigned short P_lds[64 * 72];    // [query][key]

    int tid = threadIdx.x;
    int w = tid >> 6;
    int lane = tid & 63;
    int n = lane & 15;
    int quad = lane >> 4;
    int gj = qt * 64 + w * 16 + n;

    s8v qfrag[4];
    {
        const unsigned short* qrow = QT16 + ((size_t)(b * LL) + gj) * DD;
        #pragma unroll
        for (int c = 0; c < 4; c++)
            qfrag[c] = *(const s8v*)&qrow[c * 32 + quad * 8];
    }

    f4v oacc[8];
    #pragma unroll
    for (int dt = 0; dt < 8; dt++) oacc[dt] = (f4v){0.f, 0.f, 0.f, 0.f};
    float m_run = -INFINITY, l_run = 0.f;

    // prefetch registers for tile kt (K rows + V^T rows)
    s8v kreg[4], vreg[4];
    #pragma unroll
    for (int rep = 0; rep < 4; rep++) {
        int idx = rep * 2048 + tid * 8;
        int ki = idx >> 7, kd = idx & 127;
        kreg[rep] = *(const s8v*)&KT16[((size_t)(b * LL) + ki) * DD + kd];
        int vr = idx >> 6, vc = idx & 63;
        vreg[rep] = *(const s8v*)&VT16T[((size_t)b * DD + vr) * LL + vc];
    }

    for (int kt = 0; kt <= qt; ++kt) {
        __syncthreads();   // previous iteration done reading K/V/P LDS
        #pragma unroll
        for (int rep = 0; rep < 4; rep++) {
            int idx = rep * 2048 + tid * 8;
            int ki = idx >> 7, kd = idx & 127;
            *(s8v*)&K_lds[ki * 136 + kd] = kreg[rep];
            int vr = idx >> 6, vc = idx & 63;
            *(s8v*)&Vt_lds[vr * 72 + vc] = vreg[rep];
        }
        __syncthreads();
        if (kt < qt) {   // issue next tile's global loads; consumed next iter
            #pragma unroll
            for (int rep = 0; rep < 4; rep++) {
                int idx = rep * 2048 + tid * 8;
                int ki = idx >> 7, kd = idx & 127;
                kreg[rep] = *(const s8v*)&KT16[((size_t)(b * LL) + (kt + 1) * 64 + ki) * DD + kd];
                int vr = idx >> 6, vc = idx & 63;
                vreg[rep] = *(const s8v*)&VT16T[((size_t)b * DD + vr) * LL + (kt + 1) * 64 + vc];
            }
        }

        f4v sacc[4];
        #pragma unroll
        for (int mt = 0; mt < 4; mt++) sacc[mt] = (f4v){0.f, 0.f, 0.f, 0.f};
        #pragma unroll
        for (int c = 0; c < 4; c++) {
            #pragma unroll
            for (int mt = 0; mt < 4; mt++) {
                s8v af = *(const s8v*)&K_lds[(mt * 16 + n) * 136 + c * 32 + quad * 8];
                sacc[mt] = __builtin_amdgcn_mfma_f32_16x16x32_bf16(af, qfrag[c], sacc[mt], 0, 0, 0);
            }
        }

        bool diag = (kt == qt);
        float mloc = -INFINITY;
        #pragma unroll
        for (int mt = 0; mt < 4; mt++) {
            #pragma unroll
            for (int rr = 0; rr < 4; rr++) {
                float s = sacc[mt][rr] * SCALE;
                if (diag && (kt * 64 + mt * 16 + quad * 4 + rr) > gj) s = -INFINITY;
                sacc[mt][rr] = s;
                mloc = fmaxf(mloc, s);
            }
        }
        mloc = fmaxf(mloc, __shfl_xor(mloc, 16));
        mloc = fmaxf(mloc, __shfl_xor(mloc, 32));
        float mnew = fmaxf(m_run, mloc);
        float alpha = __expf(m_run - mnew);
        m_run = mnew;

        float rsum = 0.f;
        #pragma unroll
        for (int mt = 0; mt < 4; mt++) {
            s4v pp;
            #pragma unroll
            for (int rr = 0; rr < 4; rr++) {
                float p = __expf(sacc[mt][rr] - mnew);
                rsum += p;
                pp[rr] = (short)f2bf(p);
            }
            *(s4v*)&P_lds[(w * 16 + n) * 72 + mt * 16 + quad * 4] = pp;
        }
        rsum += __shfl_xor(rsum, 16);
        rsum += __shfl_xor(rsum, 32);
        l_run = l_run * alpha + rsum;

        #pragma unroll
        for (int rr = 0; rr < 4; rr++) {
            float a_r = __shfl(alpha, quad * 4 + rr);
            #pragma unroll
            for (int dt = 0; dt < 8; dt++) oacc[dt][rr] *= a_r;
        }

        #pragma unroll
        for (int cc = 0; cc < 2; cc++) {
            s8v pf = *(const s8v*)&P_lds[(w * 16 + n) * 72 + cc * 32 + quad * 8];
            #pragma unroll
            for (int dt = 0; dt < 8; dt++) {
                s8v vf = *(const s8v*)&Vt_lds[(dt * 16 + n) * 72 + cc * 32 + quad * 8];
                oacc[dt] = __builtin_amdgcn_mfma_f32_16x16x32_bf16(pf, vf, oacc[dt], 0, 0, 0);
            }
        }
    }

    float linv = 1.f / l_run;
    #pragma unroll
    for (int rr = 0; rr < 4; rr++) {
        float li = __shfl(linv, quad * 4 + rr);
        int t = qt * 64 + w * 16 + quad * 4 + rr;
        float* orow = BvT + ((size_t)(b * LL) + t) * DD;
        #pragma unroll
        for (int dt = 0; dt < 8; dt++)
            orow[dt * 16 + n] = oacc[dt][rr] * li;
    }
}

// ---------------- head + pred fused -----------------------------------------
// O tile = Head_agg @ Bv stays in LDS (bf16); this block's O rows t0..t0+63
// are exactly the u-states for pred terms t in [t0+1, t0+64] (t<512), plus
// the t=0 (user_init) term handled by the t0==0 block.
__global__ __launch_bounds__(256) void head_kernel(
    const unsigned short* __restrict__ H16, const float* __restrict__ BvT,
    const unsigned short* __restrict__ emb16, const float* __restrict__ uinit,
    const int* __restrict__ qseq, const int* __restrict__ cseq,
    float* __restrict__ acc)
{
    int b = blockIdx.y;
    int t0 = blockIdx.x * 64;
    __shared__ unsigned short Btok[64 * 136];
    __shared__ unsigned short Hl[128 * 136];
    __shared__ unsigned short O_lds[64 * 136];
    int tid = threadIdx.x;
    {
        int t = tid >> 2, d0 = (tid & 3) * 32;
        const float* br = BvT + ((size_t)(b * LL) + t0 + t) * DD + d0;
        #pragma unroll
        for (int e = 0; e < 32; e += 8) {
            float4 x = *(const float4*)&br[e];
            float4 y = *(const float4*)&br[e + 4];
            s8v o;
            o[0] = (short)f2bf(x.x); o[1] = (short)f2bf(x.y);
            o[2] = (short)f2bf(x.z); o[3] = (short)f2bf(x.w);
            o[4] = (short)f2bf(y.x); o[5] = (short)f2bf(y.y);
            o[6] = (short)f2bf(y.z); o[7] = (short)f2bf(y.w);
            *(s8v*)&Btok[t * 136 + d0 + e] = o;
        }
    }
    {
        const unsigned short* src = H16 + (tid >> 1) * DD + (tid & 1) * 64;
        unsigned short* dst = &Hl[(tid >> 1) * 136 + (tid & 1) * 64];
        #pragma unroll
        for (int e = 0; e < 64; e += 8)
            *(s8v*)&dst[e] = *(const s8v*)&src[e];
    }
    __syncthreads();

    int w = tid >> 6, lane = tid & 63, n = lane & 15, quad = lane >> 4;
    f4v a2[2][4];
    #pragma unroll
    for (int mt = 0; mt < 2; mt++)
        #pragma unroll
        for (int nt = 0; nt < 4; nt++) a2[mt][nt] = (f4v){0.f, 0.f, 0.f, 0.f};
    #pragma unroll
    for (int c = 0; c < 4; c++) {
        s8v af0 = *(const s8v*)&Hl[(w * 32 + n) * 136 + c * 32 + quad * 8];
        s8v af1 = *(const s8v*)&Hl[(w * 32 + 16 + n) * 136 + c * 32 + quad * 8];
        #pragma unroll
        for (int nt = 0; nt < 4; nt++) {
            s8v bf = *(const s8v*)&Btok[(nt * 16 + n) * 136 + c * 32 + quad * 8];
            a2[0][nt] = __builtin_amdgcn_mfma_f32_16x16x32_bf16(af0, bf, a2[0][nt], 0, 0, 0);
            a2[1][nt] = __builtin_amdgcn_mfma_f32_16x16x32_bf16(af1, bf, a2[1][nt], 0, 0, 0);
        }
    }
    // write O tile to LDS (bf16): O_lds[t_local][r]
    #pragma unroll
    for (int mt = 0; mt < 2; mt++)
        #pragma unroll
        for (int nt = 0; nt < 4; nt++) {
            int tl = nt * 16 + n;
            int r = w * 32 + mt * 16 + quad * 4;
            #pragma unroll
            for (int rr = 0; rr < 4; rr++)
                O_lds[tl * 136 + r + rr] = f2bf(a2[mt][nt][rr]);
        }
    __syncthreads();

    // pred: 16 groups of 16 lanes, each 4 terms. term t uses u = O[t-1].
    int g = tid >> 4, sub = tid & 15;
    float local = 0.f;
    #pragma unroll
    for (int tt = 0; tt < 4; tt++) {
        int tl = g * 4 + tt;         // O row = t-1 local
        int t = t0 + tl + 1;
        if (t < LL) {
            s8v uv = *(const s8v*)&O_lds[tl * 136 + sub * 8];
            int qi = qseq[b * LL + t];
            s8v ev = *(const s8v*)&emb16[(size_t)qi * DD + sub * 8];
            float s = red16(dot8bf(uv, ev));
            if (sub == 0) {
                float c = (float)cseq[b * LL + t];
                float pred = 1.f / (1.f + __expf(-s));
                local += c * __logf(pred + EPSF) + (1.f - c) * __logf(1.f - pred + EPSF);
            }
        }
    }
    if (t0 == 0 && g == 0) {   // t = 0 term with user_init (fp32)
        int qi = qseq[b * LL];
        s8v ev = *(const s8v*)&emb16[(size_t)qi * DD + sub * 8];
        float4 u0 = *(const float4*)&uinit[sub * 8];
        float4 u1 = *(const float4*)&uinit[sub * 8 + 4];
        float s = u0.x * bf2f((unsigned short)ev[0]) + u0.y * bf2f((unsigned short)ev[1])
                + u0.z * bf2f((unsigned short)ev[2]) + u0.w * bf2f((unsigned short)ev[3])
                + u1.x * bf2f((unsigned short)ev[4]) + u1.y * bf2f((unsigned short)ev[5])
                + u1.z * bf2f((unsigned short)ev[6]) + u1.w * bf2f((unsigned short)ev[7]);
        s = red16(s);
        if (sub == 0) {
            float c = (float)cseq[b * LL];
            float pred = 1.f / (1.f + __expf(-s));
            local += c * __logf(pred + EPSF) + (1.f - c) * __logf(1.f - pred + EPSF);
        }
    }
    block_atomic_sum(local, acc + 2);
}

// ---------------- final combine ---------------------------------------------
__global__ void combine_kernel(
    const float* __restrict__ acc, const float* __restrict__ sd0p,
    const float* __restrict__ sd1p, const float* __restrict__ sdqp,
    float* __restrict__ out)
{
    if (threadIdx.x == 0 && blockIdx.x == 0) {
        float l0 = -acc[0], l1 = -acc[1], ls = -acc[2];
        float s0 = *sd0p, s1 = *sd1p, ss = *sdqp;
        float tf = l0 / (s0 * s0 + EPSF) + 400000.f * logf(s0 + EPSF)
                 + l1 / (s1 * s1 + EPSF) + 400000.f * logf(s1 + EPSF)
                 + ls / (ss * ss + EPSF) + 512.f * logf(ss + EPSF);
        out[0] = tf;
    }
}

extern "C" void kernel_launch(void* const* d_in, const int* in_sizes, int n_in,
                              void* d_out, int out_size, void* d_ws, size_t ws_size,
                              hipStream_t stream) {
    const float* emb   = (const float*)d_in[0];
    const float* Wrep  = (const float*)d_in[1];
    const float* Wq    = (const float*)d_in[2];
    const float* Wk    = (const float*)d_in[3];
    const float* Wv    = (const float*)d_in[4];
    const float* Hd    = (const float*)d_in[5];
    const float* uinit = (const float*)d_in[6];
    const float* sd0   = (const float*)d_in[7];
    const float* sd1   = (const float*)d_in[8];
    const float* sdq   = (const float*)d_in[9];
    const int* pe0 = (const int*)d_in[10];
    const int* ne0 = (const int*)d_in[11];
    const int* pe1 = (const int*)d_in[12];
    const int* ne1 = (const int*)d_in[13];
    const int* qs  = (const int*)d_in[14];
    const int* cs  = (const int*)d_in[15];

    const size_t SZ = (size_t)BB * LL * DD;   // 4,194,304
    char* base = (char*)d_ws;
    float* acc = (float*)base;                                  // 256 B
    unsigned short* emb16 = (unsigned short*)(base + 256);      // 12.8 MB
    unsigned short* W16   = emb16 + (size_t)NN * DD;            // 128 KB
    unsigned short* QT16  = W16 + 4 * DD * DD;
    unsigned short* KT16  = QT16 + SZ;
    unsigned short* VT16T = KT16 + SZ;                          // [b][128][512]
    float* BvT = (float*)(VT16T + SZ);                          // fp32

    hipMemsetAsync(acc, 0, 256, stream);

    cvt_emb_kernel<<<1024, 256, 0, stream>>>(emb, emb16);
    cvt_w_kernel<<<32, 256, 0, stream>>>(Wq, Wk, Wv, Hd, W16);

    edges_kernel<<<1536, 256, 0, stream>>>(emb16, pe0, ne0, pe1, ne1, acc);

    proj_kernel<<<dim3(8, 64), 256, 0, stream>>>(emb16, Wrep, W16, qs, cs,
                                                 QT16, KT16, VT16T);
    attn_mfma_kernel<<<512, 256, 0, stream>>>(QT16, KT16, VT16T, BvT);
    head_kernel<<<dim3(8, 64), 256, 0, stream>>>(W16 + 3 * DD * DD, BvT,
                                                 emb16, uinit, qs, cs, acc);

    combine_kernel<<<1, 64, 0, stream>>>(acc, sd0, sd1, sdq, (float*)d_out);
}